// Round 11
// baseline (1120.833 us; speedup 1.0000x reference)
//
#include <hip/hip_runtime.h>
#include <hip/hip_bf16.h>
#include <hip/hip_cooperative_groups.h>

namespace cg = cooperative_groups;

typedef __hip_bfloat16 bf16;
typedef __attribute__((ext_vector_type(8))) short short8;
typedef __attribute__((ext_vector_type(4))) float f32x4;
typedef __attribute__((ext_vector_type(4))) unsigned u32x4;

#define MAXN 0.996f      // (1 - 4e-3)/sqrt(c), c=1
#define MINN 1e-15f

__device__ __forceinline__ float b2f(short s) {
    union { unsigned u; float f; } c; c.u = ((unsigned)(unsigned short)s) << 16; return c.f;
}
__device__ __forceinline__ short f2b(float f) {   // RNE bf16
    union { float f; unsigned u; } c; c.f = f;
    unsigned r = c.u + 0x7FFF + ((c.u >> 16) & 1);
    return (short)(r >> 16);
}
__device__ __forceinline__ float lo16f(unsigned u) {
    union { unsigned u; float f; } c; c.u = u << 16; return c.f;
}
__device__ __forceinline__ float hi16f(unsigned u) {
    union { unsigned u; float f; } c; c.u = u & 0xFFFF0000u; return c.f;
}
__device__ __forceinline__ unsigned pk2(float x, float y) {
    return (unsigned)(unsigned short)f2b(x) | ((unsigned)(unsigned short)f2b(y) << 16);
}
__device__ __forceinline__ float cv(short v) { return b2f(v); }
__device__ __forceinline__ float cv(float v) { return v; }
__device__ __forceinline__ short tb(short v) { return v; }
__device__ __forceinline__ short tb(float v) { return f2b(v); }
__device__ __forceinline__ short8 ld8(const short* p) { return *(const short8*)p; }
__device__ __forceinline__ short8 ld8(const float* p) {
    float4 a = *(const float4*)p, b = *(const float4*)(p + 4);
    short8 r;
    r[0] = f2b(a.x); r[1] = f2b(a.y); r[2] = f2b(a.z); r[3] = f2b(a.w);
    r[4] = f2b(b.x); r[5] = f2b(b.y); r[6] = f2b(b.z); r[7] = f2b(b.w);
    return r;
}
__device__ __forceinline__ void ldf8(const short* p, float* f) {
    short8 v = *(const short8*)p;
#pragma unroll
    for (int j = 0; j < 8; ++j) f[j] = b2f(v[j]);
}
__device__ __forceinline__ void ldf8(const float* p, float* f) {
    float4 a = *(const float4*)p, b = *(const float4*)(p + 4);
    f[0] = a.x; f[1] = a.y; f[2] = a.z; f[3] = a.w;
    f[4] = b.x; f[5] = b.y; f[6] = b.z; f[7] = b.w;
}
__device__ __forceinline__ void st(short* p, float v) { *p = f2b(v); }
__device__ __forceinline__ void st(float* p, float v) { *p = v; }

__device__ __forceinline__ float red16(float v) {
#pragma unroll
    for (int m = 1; m < 16; m <<= 1) v += __shfl_xor(v, m);
    return v;
}
__device__ __forceinline__ float red8(float v) {
#pragma unroll
    for (int m = 1; m < 8; m <<= 1) v += __shfl_xor(v, m);
    return v;
}

// ---- fast transcendentals (hardware v_exp/v_log/v_rcp; err ~1e-6 rel,
// far below the bf16 quantization of every data buffer) ----
__device__ __forceinline__ float tanh_(float x) {
    float ax = fminf(fabsf(x), 20.f);
    float e = __expf(-2.f * ax);
    float t = (1.f - e) * __builtin_amdgcn_rcpf(1.f + e);
    return copysignf(t, x);
}
__device__ __forceinline__ float artanh_(float x) {
    // callers pass x >= 0 (norms)
    x = fminf(x, 1.f - 1e-7f);
    float x2 = x * x;
    float smal = x * (1.f + x2 * (0.33333334f + x2 * (0.2f + x2 * (0.14285715f + x2 * 0.11111111f))));
    float big = 0.5f * __logf((1.f + x) * __builtin_amdgcn_rcpf(1.f - x));
    return (x < 0.25f) ? smal : big;
}
__device__ __forceinline__ float sigmoidf_(float x) {
    float e = __expf(-x);
    return __builtin_amdgcn_rcpf(1.f + e);
}

// fragment-order index for [DOUT][128] weights: unit ((nt*4+kk)*64+lane), elem e
__device__ __forceinline__ int fragidx(int d, int j) {
    int nt = d >> 4, l15 = d & 15;
    int kk = j >> 5, quad = (j >> 3) & 3, e = j & 7;
    return (((nt << 2) + kk) * 64 + (quad << 4) + l15) * 8 + e;
}

// ---------------- prep body (block 0 of k_prep_all) ----------------
template <typename T>
__device__ void prep_body(const T* b1, const T* b2, const T* bl, const T* bih,
                          const T* bhh, const T* Q, const T* ratt,
                          const T* Wih, const T* Whh,
                          float* hb1, float* y2a, float* hb2, float* y2b,
                          float* blf, float* bs256, float* ratf,
                          short* QT, short* Wc, float* sb) {
    int t = threadIdx.x;
    float v1 = (t < 128) ? cv(b1[t]) : 0.f;
    sb[t] = v1 * v1; __syncthreads();
    for (int d = 128; d > 0; d >>= 1) { if (t < d) sb[t] += sb[t + d]; __syncthreads(); }
    float n2a = sb[0]; __syncthreads();
    {
        float un = fmaxf(sqrtf(n2a), MINN);
        float e = tanh_(un), tt = e / un;
        float s = (e > MAXN) ? MAXN / e : 1.f;
        if (t < 128) hb1[t] = s * tt * v1;
        if (t == 0) { float hn = s * e; y2a[0] = hn * hn; }
    }
    float v2 = (t < 64) ? cv(b2[t]) : 0.f;
    sb[t] = v2 * v2; __syncthreads();
    for (int d = 128; d > 0; d >>= 1) { if (t < d) sb[t] += sb[t + d]; __syncthreads(); }
    float n2b = sb[0]; __syncthreads();
    {
        float un = fmaxf(sqrtf(n2b), MINN);
        float e = tanh_(un), tt = e / un;
        float s = (e > MAXN) ? MAXN / e : 1.f;
        if (t < 64) hb2[t] = s * tt * v2;
        if (t == 0) { float hn = s * e; y2b[0] = hn * hn; }
    }
    for (int i = t; i < 64; i += 256) {
        blf[i] = cv(bl[i]);
        ratf[i] = cv(ratt[i]);
    }
    {
        float v = (t < 192) ? (cv(bih[t]) + cv(bhh[t])) : cv(bhh[t - 64]);
        bs256[t] = v;
    }
    for (int i = t; i < 4096; i += 256) { int k = i >> 6, n = i & 63; QT[n * 64 + k] = tb(Q[k * 64 + n]); }
    // GRU combined weight in MFMA-fragment order
    for (int i = t; i < 256 * 128; i += 256) {
        int d = i >> 7, j = i & 127;
        short v;
        if (d < 192) v = (j < 64) ? tb(Wih[d * 64 + j]) : tb(Whh[d * 64 + (j - 64)]);
        else         v = (j < 64) ? (short)0 : tb(Whh[(d - 64) * 64 + (j - 64)]);
        Wc[fragidx(d, j)] = v;
    }
}

template <typename T>
__device__ void wcvt_body(int i, const T* Wl, const T* W1, const T* W2,
                          short* Wlb, short* W1b, short* W2b) {
    if (i < 8192) {
        Wlb[fragidx(i >> 7, i & 127)] = tb(Wl[i]);
    } else if (i < 24576) {
        int i2 = i - 8192;
        W1b[fragidx(i2 >> 7, i2 & 127)] = tb(W1[i2]);
    } else if (i < 32768) {
        int i2 = i - 24576;
        W2b[fragidx(i2 >> 7, i2 & 127)] = tb(W2[i2]);
    }
}

// prep + weight conversion, dtype-branched internally. Launch 129 blocks.
__global__ __launch_bounds__(256) void k_prep_all(
        const void* b1, const void* b2, const void* bl, const void* bih,
        const void* bhh, const void* Q, const void* ratt,
        const void* Wih, const void* Whh,
        const void* Wl, const void* W1, const void* W2,
        float* hb1, float* y2a, float* hb2, float* y2b,
        float* blf, float* bs256, float* ratf,
        short* QT, short* Wc,
        short* Wlb, short* W1b, short* W2b, const int* flag) {
    __shared__ float sb[256];
    int f = *flag;
    if (blockIdx.x == 0) {
        if (f) prep_body<float>((const float*)b1, (const float*)b2, (const float*)bl,
                                (const float*)bih, (const float*)bhh, (const float*)Q,
                                (const float*)ratt, (const float*)Wih, (const float*)Whh,
                                hb1, y2a, hb2, y2b, blf, bs256, ratf, QT, Wc, sb);
        else   prep_body<short>((const short*)b1, (const short*)b2, (const short*)bl,
                                (const short*)bih, (const short*)bhh, (const short*)Q,
                                (const short*)ratt, (const short*)Wih, (const short*)Whh,
                                hb1, y2a, hb2, y2b, blf, bs256, ratf, QT, Wc, sb);
    } else {
        int i = (blockIdx.x - 1) * 256 + threadIdx.x;
        if (f) wcvt_body<float>(i, (const float*)Wl, (const float*)W1, (const float*)W2, Wlb, W1b, W2b);
        else   wcvt_body<short>(i, (const short*)Wl, (const short*)W1, (const short*)W2, Wlb, W1b, W2b);
    }
}

// ============ cooperative CSR build: zero+detect | count | scan | dis | fill ============
// One launch replaces detect + memset + count + 3-phase scan + fill (7 stream ops).
// All phases grid-stride; every thread reaches every grid.sync().
#define SC_CHUNK 2048
__global__ __launch_bounds__(256) void k_csr(const int* __restrict__ src, const int* __restrict__ dst,
                                             int E, int N,
                                             const void* hid, int* __restrict__ flag,
                                             int* __restrict__ cnt, int* __restrict__ fillc,
                                             int* __restrict__ rowptr, float* __restrict__ dis,
                                             int* __restrict__ bsum, int2* __restrict__ edge) {
    cg::grid_group grid = cg::this_grid();
    __shared__ int sb[256];
    int t = threadIdx.x;
    int b = blockIdx.x;
    int gid = b * 256 + t;
    int gs = gridDim.x * 256;
    int nbs = (N + SC_CHUNK - 1) / SC_CHUNK;

    // ---- phase A: zero cnt/fillc; block 0 also runs the dtype detector ----
    for (int i = gid; i < N; i += gs) { cnt[i] = 0; fillc[i] = 0; }
    if (b == 0) {
        const short* p = (const short*)hid;
        int bad = 0;
        for (int i = t; i < 4096; i += 256) {
            unsigned u = (unsigned)(unsigned short)p[i];
            unsigned ex = (u >> 7) & 0xFF;
            if (bad == 0 && ex >= 128) bad = 1;   // |v|>=2 or NaN/Inf -> not in-ball bf16
        }
        if (t == 0) sb[0] = 0;
        __syncthreads();
        if (bad) atomicOr(&sb[0], 1);
        __syncthreads();
        if (t == 0) *flag = sb[0];
    }
    grid.sync();

    // ---- phase B: degree count ----
    for (int i = gid; i < E; i += gs) atomicAdd(&cnt[src[i]], 1);
    grid.sync();

    // ---- phase C1: per-chunk sums (blocks < nbs) ----
    if (b < nbs) {
        int base = b * SC_CHUNK + t * 8;
        int s = 0;
#pragma unroll
        for (int j = 0; j < 8; ++j) { int i = base + j; if (i < N) s += cnt[i]; }
        sb[t] = s; __syncthreads();
        for (int d = 128; d > 0; d >>= 1) { if (t < d) sb[t] += sb[t + d]; __syncthreads(); }
        if (t == 0) bsum[b] = sb[0];
    }
    grid.sync();

    // ---- phase C2: block 0 exclusive-scans the nbs chunk sums (nbs <= 1024) ----
    if (b == 0) {
        int base4 = t * 4;
        int vv[4]; int s = 0;
#pragma unroll
        for (int j = 0; j < 4; ++j) { int i = base4 + j; vv[j] = (i < nbs) ? bsum[i] : 0; s += vv[j]; }
        sb[t] = s; __syncthreads();
        for (int d = 1; d < 256; d <<= 1) {
            int u = (t >= d) ? sb[t - d] : 0; __syncthreads();
            sb[t] += u; __syncthreads();
        }
        int run = (t == 0) ? 0 : sb[t - 1];
#pragma unroll
        for (int j = 0; j < 4; ++j) {
            int i = base4 + j;
            if (i < nbs) bsum[i] = run;
            run += vv[j];
        }
        if (t == 255) bsum[nbs] = run;   // grand total (tail vv are 0)
    }
    grid.sync();

    // ---- phase C3: write rowptr + dis (blocks < nbs) ----
    if (b < nbs) {
        int base = b * SC_CHUNK + t * 8;
        int v[8]; int s = 0;
#pragma unroll
        for (int j = 0; j < 8; ++j) { int i = base + j; v[j] = (i < N) ? cnt[i] : 0; s += v[j]; }
        sb[t] = s; __syncthreads();
        for (int d = 1; d < 256; d <<= 1) {
            int u = (t >= d) ? sb[t - d] : 0; __syncthreads();
            sb[t] += u; __syncthreads();
        }
        int run = bsum[b] + ((t == 0) ? 0 : sb[t - 1]);
#pragma unroll
        for (int j = 0; j < 8; ++j) {
            int i = base + j;
            if (i < N) {
                rowptr[i] = run;
                dis[i] = 1.f / sqrtf((float)(v[j] + 1));
            }
            run += v[j];
        }
        if (b == 0 && t == 0) rowptr[N] = bsum[nbs];
    }
    grid.sync();

    // ---- phase D: fill edge records {col, w = dis[s]*dis[d]} ----
    for (int i = gid; i < E; i += gs) {
        int s = src[i], d = dst[i];
        int p = rowptr[s] + atomicAdd(&fillc[s], 1);
        int2 e; e.x = d; e.y = __float_as_int(dis[s] * dis[d]);
        edge[p] = e;
    }
}

// --------- fused HTA attention: logmap0 -> scores -> ONLINE softmax -> combine ----
template <typename T>
__device__ void att_body(const T* hid, const short* QT, const float* ratf,
                         bf16* Hb, int N, int win) {
    int wid = threadIdx.x >> 6, lane = threadIdx.x & 63;
    int row0 = blockIdx.x * 64 + wid * 16;
    if (row0 >= N) return;
    int l15 = lane & 15, quad = lane >> 4;
    int node = row0 + l15;
    int nodeC = (node < N) ? node : (N - 1);
    // hoisted QT fragments (loop-invariant)
    short8 qb0[4], qb1[4];
    float rw[4];
#pragma unroll
    for (int nt = 0; nt < 4; ++nt) {
        qb0[nt] = *(const short8*)(QT + (size_t)(nt * 16 + l15) * 64 + quad * 8);
        qb1[nt] = *(const short8*)(QT + (size_t)(nt * 16 + l15) * 64 + 32 + quad * 8);
        rw[nt] = ratf[nt * 16 + l15];
    }
    float m = -1e30f, srun = 0.f;
    float h[16];
#pragma unroll
    for (int j = 0; j < 16; ++j) h[j] = 0.f;
    for (int w = 0; w < win; ++w) {
        const T* Hrow = hid + ((size_t)w * N + nodeC) * 64 + quad * 8;
        float f0[8], f1[8];
        ldf8(Hrow, f0); ldf8(Hrow + 32, f1);
        float sq = 0.f;
#pragma unroll
        for (int j = 0; j < 8; ++j) sq += f0[j] * f0[j] + f1[j] * f1[j];
        sq += __shfl_xor(sq, 16); sq += __shfl_xor(sq, 32);
        float pn = fmaxf(sqrtf(sq), MINN);
        float lt = artanh_(pn) / pn;
        short8 s0, s1;
#pragma unroll
        for (int j = 0; j < 8; ++j) { s0[j] = f2b(lt * f0[j]); s1[j] = f2b(lt * f1[j]); }
        f32x4 acc[4];
#pragma unroll
        for (int nt = 0; nt < 4; ++nt) acc[nt] = (f32x4){0.f, 0.f, 0.f, 0.f};
#pragma unroll
        for (int nt = 0; nt < 4; ++nt) {
            acc[nt] = __builtin_amdgcn_mfma_f32_16x16x32_bf16(s0, qb0[nt], acc[nt], 0, 0, 0);
            acc[nt] = __builtin_amdgcn_mfma_f32_16x16x32_bf16(s1, qb1[nt], acc[nt], 0, 0, 0);
        }
        float er[4];
#pragma unroll
        for (int r = 0; r < 4; ++r) {
            float s = 0.f;
#pragma unroll
            for (int nt = 0; nt < 4; ++nt) s += tanh_(acc[nt][r]) * rw[nt];
            er[r] = red16(s);       // all lanes of this quad hold E[row0+quad*4+r]
        }
        // broadcast: this lane needs E of node row0+l15 (held by quad l15>>2, slot l15&3)
        int srcLane = (l15 >> 2) << 4;
        float t0 = __shfl(er[0], srcLane);
        float t1 = __shfl(er[1], srcLane);
        float t2 = __shfl(er[2], srcLane);
        float t3 = __shfl(er[3], srcLane);
        int rr = l15 & 3;
        float Eval = (rr == 0) ? t0 : (rr == 1) ? t1 : (rr == 2) ? t2 : t3;
        // online softmax update
        float mn = fmaxf(m, Eval);
        float c = __expf(m - mn);
        float p = __expf(Eval - mn);
        m = mn;
        srun = srun * c + p;
#pragma unroll
        for (int j = 0; j < 8; ++j) {
            h[j]     = h[j]     * c + p * (lt * f0[j]);
            h[8 + j] = h[8 + j] * c + p * (lt * f1[j]);
        }
    }
    if (node < N) {
        float den = srun * (float)win;
        short8 o0, o1;
#pragma unroll
        for (int j = 0; j < 8; ++j) { o0[j] = f2b(h[j] / den); o1[j] = f2b(h[8 + j] / den); }
        *(short8*)((short*)Hb + (size_t)node * 64 + quad * 8) = o0;
        *(short8*)((short*)Hb + (size_t)node * 64 + 32 + quad * 8) = o1;
    }
}
__global__ __launch_bounds__(256) void k_att(const void* hid, const short* __restrict__ QT,
                                             const float* __restrict__ ratf,
                                             bf16* __restrict__ Hb, int N, int win, const int* flag) {
    if (*flag) att_body<float>((const float*)hid, QT, ratf, Hb, N, win);
    else       att_body<short>((const short*)hid, QT, ratf, Hb, N, win);
}

// --------- FUSED: initial linear + toHyperX + concat -> (LDS) -> conv1 linear ----
#define SXSTR 136
template <typename T>
__device__ void lin0c1_body(const T* feat, const short* Wl, const float* blf, const T* hid,
                            int win, const short* W1, const float* hb1, const float* y2p,
                            bf16* outA, int N, short* sX) {
    int t = threadIdx.x;
    int wid = t >> 6, lane = t & 63;
    int row0 = blockIdx.x * 64 + wid * 16;
    if (row0 >= N) return;
    int l15 = lane & 15, quad = lane >> 4;
    short* sx = sX + wid * 16 * SXSTR;     // this wave's 16x128 tile (padded)
    // ---- phase 1: lin0 GEMM (feat @ Wl^T) ----
    const short8* Wf = (const short8*)Wl;
    f32x4 acc[4];
#pragma unroll
    for (int nt = 0; nt < 4; ++nt) acc[nt] = (f32x4){0.f, 0.f, 0.f, 0.f};
    const T* Arow = feat + (size_t)(row0 + l15) * 128 + quad * 8;
#pragma unroll
    for (int kk = 0; kk < 4; ++kk) {
        short8 a = ld8(Arow + kk * 32);
#pragma unroll
        for (int nt = 0; nt < 4; ++nt) {
            short8 b = Wf[(nt * 4 + kk) * 64 + lane];
            acc[nt] = __builtin_amdgcn_mfma_f32_16x16x32_bf16(a, b, acc[nt], 0, 0, 0);
        }
    }
    float bv[4];
#pragma unroll
    for (int nt = 0; nt < 4; ++nt) bv[nt] = blf[nt * 16 + l15];
    float xn_r[4];
#pragma unroll
    for (int r = 0; r < 4; ++r) {
        int row = row0 + quad * 4 + r;
        float g[4], u2 = 0.f;
#pragma unroll
        for (int nt = 0; nt < 4; ++nt) { g[nt] = acc[nt][r] + bv[nt]; u2 += g[nt] * g[nt]; }
        u2 = red16(u2);
        float un = fmaxf(sqrtf(u2), MINN);
        float e = tanh_(un), tt = e / un;
        float s1 = (e > MAXN) ? MAXN / e : 1.f;
        float x0n = s1 * e;
        float hv[4], h2 = 0.f;
#pragma unroll
        for (int nt = 0; nt < 4; ++nt) {
            hv[nt] = cv(hid[((size_t)(win - 1) * N + row) * 64 + nt * 16 + l15]);
            h2 += hv[nt] * hv[nt];
        }
        h2 = red16(h2);
        float n128 = sqrtf(x0n * x0n + h2);
        float s2 = (n128 > MAXN) ? MAXN / n128 : 1.f;
        short* srow = sx + (quad * 4 + r) * SXSTR;
#pragma unroll
        for (int nt = 0; nt < 4; ++nt) {
            srow[nt * 16 + l15] = f2b(s2 * s1 * tt * g[nt]);
            srow[64 + nt * 16 + l15] = f2b(s2 * hv[nt]);
        }
        xn_r[r] = fmaxf(fminf(n128, MAXN), MINN);
    }
    // ---- phase 2: conv1 GEMM from LDS (wave-internal dep; no barrier) ----
    const short8* W1f = (const short8*)W1;
    f32x4 acc2[8];
#pragma unroll
    for (int nt = 0; nt < 8; ++nt) acc2[nt] = (f32x4){0.f, 0.f, 0.f, 0.f};
    const short* Ax = sx + l15 * SXSTR + quad * 8;
#pragma unroll
    for (int kk = 0; kk < 4; ++kk) {
        short8 a = *(const short8*)(Ax + kk * 32);
#pragma unroll
        for (int nt = 0; nt < 8; ++nt) {
            short8 b = W1f[(nt * 4 + kk) * 64 + lane];
            acc2[nt] = __builtin_amdgcn_mfma_f32_16x16x32_bf16(a, b, acc2[nt], 0, 0, 0);
        }
    }
    float y2 = y2p[0];
    float hbv[8];
#pragma unroll
    for (int nt = 0; nt < 8; ++nt) hbv[nt] = hb1[nt * 16 + l15];
#pragma unroll
    for (int r = 0; r < 4; ++r) {
        int row = row0 + quad * 4 + r;
        float mx[8], m2 = 0.f;
#pragma unroll
        for (int nt = 0; nt < 8; ++nt) { mx[nt] = acc2[nt][r]; m2 += mx[nt] * mx[nt]; }
        m2 = red16(m2);
        float mxn = fmaxf(sqrtf(m2), MINN);
        float xn = xn_r[r];
        float at = artanh_(xn);
        float f = (m2 == 0.f) ? 0.f : tanh_(mxn / xn * at) / mxn;
        float rn = f * mxn;
        float s1 = (rn > MAXN) ? MAXN / rn : 1.f;
        float a_ = s1 * f, mvn = s1 * rn;
        float x2 = mvn * mvn;
        float xy = 0.f;
#pragma unroll
        for (int nt = 0; nt < 8; ++nt) xy += (a_ * mx[nt]) * hbv[nt];
        xy = red16(xy);
        float co = 1.f + 2.f * xy + y2, cx = 1.f - x2;
        float den = fmaxf(1.f + 2.f * xy + x2 * y2, MINN);
        float o[8], on2 = 0.f;
#pragma unroll
        for (int nt = 0; nt < 8; ++nt) { o[nt] = (co * a_ * mx[nt] + cx * hbv[nt]) / den; on2 += o[nt] * o[nt]; }
        on2 = red16(on2);
        float on = sqrtf(on2);
        float s3 = (on > MAXN) ? MAXN / on : 1.f;
        float hn = fmaxf(s3 * on, MINN);
        float lt = artanh_(hn) / hn;
#pragma unroll
        for (int nt = 0; nt < 8; ++nt)
            ((short*)outA)[(size_t)row * 128 + nt * 16 + l15] = f2b(lt * s3 * o[nt]);
    }
}
__global__ __launch_bounds__(256) void k_lin0c1(const void* feat, const short* __restrict__ Wl,
                                                const float* __restrict__ blf, const void* hid,
                                                int win, const short* __restrict__ W1,
                                                const float* __restrict__ hb1, const float* __restrict__ y2a,
                                                bf16* __restrict__ outA, int N, const int* flag) {
    __shared__ short sX[4 * 16 * SXSTR];   // 17408 B
    if (*flag) lin0c1_body<float>((const float*)feat, Wl, blf, (const float*)hid, win, W1, hb1, y2a, outA, N, sX);
    else       lin0c1_body<short>((const short*)feat, Wl, blf, (const short*)hid, win, W1, hb1, y2a, outA, N, sX);
}

// ------- conv2 linear: GEMM fused with matvec->proj->madd(hb)->proj->logmap0 ----
template <int DOUT>
__global__ __launch_bounds__(256) void k_conv_lin(const bf16* __restrict__ in, const short* __restrict__ W,
                                                  const float* __restrict__ hb, const float* __restrict__ y2p,
                                                  const float* __restrict__ xnorm,
                                                  bf16* __restrict__ out, int N) {
    constexpr int NT = DOUT / 16;
    int t = threadIdx.x;
    int wid = t >> 6, lane = t & 63;
    int row0 = blockIdx.x * 64 + wid * 16;
    if (row0 >= N) return;
    int l15 = lane & 15, quad = lane >> 4;
    const short8* Wf = (const short8*)W;
    f32x4 acc[NT];
#pragma unroll
    for (int nt = 0; nt < NT; ++nt) acc[nt] = (f32x4){0.f, 0.f, 0.f, 0.f};
    const short* Arow = (const short*)in + (size_t)(row0 + l15) * 128 + quad * 8;
#pragma unroll
    for (int kk = 0; kk < 4; ++kk) {
        short8 a = *(const short8*)(Arow + kk * 32);
#pragma unroll
        for (int nt = 0; nt < NT; ++nt) {
            short8 b = Wf[(nt * 4 + kk) * 64 + lane];
            acc[nt] = __builtin_amdgcn_mfma_f32_16x16x32_bf16(a, b, acc[nt], 0, 0, 0);
        }
    }
    float y2 = y2p[0];
    float hbv[NT];
#pragma unroll
    for (int nt = 0; nt < NT; ++nt) hbv[nt] = hb[nt * 16 + l15];
#pragma unroll
    for (int r = 0; r < 4; ++r) {
        int row = row0 + quad * 4 + r;
        float mx[NT], m2 = 0.f;
#pragma unroll
        for (int nt = 0; nt < NT; ++nt) { mx[nt] = acc[nt][r]; m2 += mx[nt] * mx[nt]; }
        m2 = red16(m2);
        float mxn = fmaxf(sqrtf(m2), MINN);
        float xn = xnorm[row];
        float at = artanh_(xn);
        float f = (m2 == 0.f) ? 0.f : tanh_(mxn / xn * at) / mxn;
        float rn = f * mxn;
        float s1 = (rn > MAXN) ? MAXN / rn : 1.f;
        float a_ = s1 * f, mvn = s1 * rn;
        float x2 = mvn * mvn;
        float xy = 0.f;
#pragma unroll
        for (int nt = 0; nt < NT; ++nt) xy += (a_ * mx[nt]) * hbv[nt];
        xy = red16(xy);
        float co = 1.f + 2.f * xy + y2, cx = 1.f - x2;
        float den = fmaxf(1.f + 2.f * xy + x2 * y2, MINN);
        float o[NT], on2 = 0.f;
#pragma unroll
        for (int nt = 0; nt < NT; ++nt) { o[nt] = (co * a_ * mx[nt] + cx * hbv[nt]) / den; on2 += o[nt] * o[nt]; }
        on2 = red16(on2);
        float on = sqrtf(on2);
        float s3 = (on > MAXN) ? MAXN / on : 1.f;
        float hn = fmaxf(s3 * on, MINN);
        float lt = artanh_(hn) / hn;
#pragma unroll
        for (int nt = 0; nt < NT; ++nt)
            ((short*)out)[(size_t)row * 128 + nt * 16 + l15] = f2b(lt * s3 * o[nt]);
    }
}

// --------- agg (conv1, D=128): 4 nodes/wave, 16 lanes/node, dwordx4 -------
__global__ __launch_bounds__(256) void k_agg2(const bf16* __restrict__ xt, const int* __restrict__ rowptr,
                                              const int2* __restrict__ edge,
                                              const float* __restrict__ dis,
                                              bf16* __restrict__ out, float* __restrict__ xnorm, int N) {
    int wid = threadIdx.x >> 6, lane = threadIdx.x & 63;
    int g = lane >> 4, l15 = lane & 15;
    int i = blockIdx.x * 16 + wid * 4 + g;
    bool act = (i < N);
    int ii = act ? i : (N - 1);
    const u32x4* xq = (const u32x4*)xt;            // 16 u32x4 per 128-feat row
    float di = dis[ii];
    float w0 = di * di;
    u32x4 d0 = xq[(size_t)ii * 16 + l15];
    float a[8];
#pragma unroll
    for (int k = 0; k < 4; ++k) { a[2 * k] = w0 * lo16f(d0[k]); a[2 * k + 1] = w0 * hi16f(d0[k]); }
    int e0 = rowptr[ii], e1 = act ? rowptr[ii + 1] : e0;
    for (int j = e0; j < e1; ++j) {
        int2 e = edge[j];
        float w = __int_as_float(e.y);
        u32x4 d = xq[(size_t)e.x * 16 + l15];
#pragma unroll
        for (int k = 0; k < 4; ++k) { a[2 * k] += w * lo16f(d[k]); a[2 * k + 1] += w * hi16f(d[k]); }
    }
    float sq = 0.f;
#pragma unroll
    for (int k = 0; k < 8; ++k) sq += a[k] * a[k];
    float an = fmaxf(sqrtf(red16(sq)), MINN);
    float e1t = tanh_(an), t1 = e1t / an;
    float s1 = (e1t > MAXN) ? MAXN / e1t : 1.f;
    float hn = fmaxf(s1 * e1t, MINN);
    float lt = artanh_(hn) / hn;
    float sht = s1 * t1 * lt;
    float v[8], v2 = 0.f;
#pragma unroll
    for (int k = 0; k < 8; ++k) {
        float t = sht * a[k];
        t = (t >= 0.f) ? t : 0.01f * t;
        v[k] = t; v2 += t * t;
    }
    float tn = fmaxf(sqrtf(red16(v2)), MINN);
    float e2 = tanh_(tn), t2 = e2 / tn;
    float s2 = (e2 > MAXN) ? MAXN / e2 : 1.f;
    float sc = s2 * t2;
    if (act) {
        u32x4 o;
#pragma unroll
        for (int k = 0; k < 4; ++k) o[k] = pk2(sc * v[2 * k], sc * v[2 * k + 1]);
        ((u32x4*)out)[(size_t)i * 16 + l15] = o;
        if (l15 == 0) xnorm[i] = fmaxf(fminf(e2, MAXN), MINN);
    }
}

// --------- agg (conv2, D=64) + FINAL logmap0: 8 nodes/wave, 8 lanes/node --
__global__ __launch_bounds__(256) void k_agg1f(const bf16* __restrict__ xt, const int* __restrict__ rowptr,
                                               const int2* __restrict__ edge,
                                               const float* __restrict__ dis,
                                               bf16* __restrict__ out, const bf16* __restrict__ Hb, int N) {
    int wid = threadIdx.x >> 6, lane = threadIdx.x & 63;
    int g = lane >> 3, l7 = lane & 7;
    int i = blockIdx.x * 32 + wid * 8 + g;
    bool act = (i < N);
    int ii = act ? i : (N - 1);
    const u32x4* xq = (const u32x4*)xt;            // row stride 16 u32x4; feats = first 8
    float di = dis[ii];
    float w0 = di * di;
    u32x4 d0 = xq[(size_t)ii * 16 + l7];
    float a[8];
#pragma unroll
    for (int k = 0; k < 4; ++k) { a[2 * k] = w0 * lo16f(d0[k]); a[2 * k + 1] = w0 * hi16f(d0[k]); }
    int e0 = rowptr[ii], e1 = act ? rowptr[ii + 1] : e0;
    for (int j = e0; j < e1; ++j) {
        int2 e = edge[j];
        float w = __int_as_float(e.y);
        u32x4 d = xq[(size_t)e.x * 16 + l7];
#pragma unroll
        for (int k = 0; k < 4; ++k) { a[2 * k] += w * lo16f(d[k]); a[2 * k + 1] += w * hi16f(d[k]); }
    }
    float sq = 0.f;
#pragma unroll
    for (int k = 0; k < 8; ++k) sq += a[k] * a[k];
    float an = fmaxf(sqrtf(red8(sq)), MINN);
    float e1t = tanh_(an), t1 = e1t / an;
    float s1 = (e1t > MAXN) ? MAXN / e1t : 1.f;
    float hn = fmaxf(s1 * e1t, MINN);
    float lt = artanh_(hn) / hn;
    float sht = s1 * t1 * lt;
    float v[8], v2 = 0.f;
#pragma unroll
    for (int k = 0; k < 8; ++k) {
        float t = sht * a[k];
        t = (t >= 0.f) ? t : 0.01f * t;
        v[k] = t; v2 += t * t;
    }
    float tn = fmaxf(sqrtf(red8(v2)), MINN);
    float e2 = tanh_(tn), t2 = e2 / tn;
    float s2 = (e2 > MAXN) ? MAXN / e2 : 1.f;
    float sc = s2 * t2;
    float xnf = fmaxf(fminf(s2 * e2, MAXN), MINN);
    float lt2 = artanh_(xnf) / xnf;
    sc *= lt2;
    if (act) {
        u32x4 o;
#pragma unroll
        for (int k = 0; k < 4; ++k) o[k] = pk2(sc * v[2 * k], sc * v[2 * k + 1]);
        u32x4* od = (u32x4*)out;
        od[(size_t)i * 16 + l7] = o;
        od[(size_t)i * 16 + 8 + l7] = ((const u32x4*)Hb)[(size_t)i * 8 + l7];
    }
}

// --------- GRU fused + expmap0/proj -> out (dtype-branched) -----
template <typename OT>
__device__ void gru_body(const bf16* cat, const float* bs, const bf16* Hb,
                         OT* out, int N, const short8* sW) {
    int t = threadIdx.x;
    int wid = t >> 6, lane = t & 63;
    int row0 = blockIdx.x * 64 + wid * 16;
    if (row0 >= N) return;
    int l15 = lane & 15, quad = lane >> 4;
    f32x4 acc[16];
#pragma unroll
    for (int nt = 0; nt < 16; ++nt) acc[nt] = (f32x4){0.f, 0.f, 0.f, 0.f};
    const short* Arow = (const short*)cat + (size_t)(row0 + l15) * 128 + quad * 8;
#pragma unroll
    for (int kk = 0; kk < 4; ++kk) {
        short8 a = *(const short8*)(Arow + kk * 32);
#pragma unroll
        for (int nt = 0; nt < 16; ++nt) {
            short8 b = sW[(nt * 4 + kk) * 64 + lane];
            acc[nt] = __builtin_amdgcn_mfma_f32_16x16x32_bf16(a, b, acc[nt], 0, 0, 0);
        }
    }
#pragma unroll
    for (int r = 0; r < 4; ++r) {
        int row = row0 + quad * 4 + r;
        float zv[4], z2 = 0.f;
#pragma unroll
        for (int nt = 0; nt < 4; ++nt) {
            int c = nt * 16 + l15;
            float gr = acc[nt][r] + bs[c];
            float gz = acc[nt + 4][r] + bs[c + 64];
            float gn = acc[nt + 8][r] + bs[c + 128];
            float hn = acc[nt + 12][r] + bs[c + 192];
            float hv = b2f(((const short*)Hb)[(size_t)row * 64 + c]);
            float rr = sigmoidf_(gr), zz = sigmoidf_(gz);
            float nn = tanh_(gn + (rr - 1.f) * hn);
            zv[nt] = (1.f - zz) * nn + zz * hv;
            z2 += zv[nt] * zv[nt];
        }
        z2 = red16(z2);
        float un = fmaxf(sqrtf(z2), MINN);
        float e = tanh_(un), tt = e / un;
        float s = (e > MAXN) ? MAXN / e : 1.f;
#pragma unroll
        for (int nt = 0; nt < 4; ++nt)
            st(&out[(size_t)row * 64 + nt * 16 + l15], s * tt * zv[nt]);
    }
}
__global__ __launch_bounds__(256) void k_gru(const bf16* __restrict__ cat, const short* __restrict__ Wc,
                                             const float* __restrict__ bs, const bf16* __restrict__ Hb,
                                             void* out, int N, const int* flag) {
    __shared__ short8 sW[4096];        // 64KB: 256x128 bf16, single allocation for both paths
    int t = threadIdx.x;
#pragma unroll
    for (int u = 0; u < 16; ++u) sW[u * 256 + t] = ((const short8*)Wc)[u * 256 + t];
    __syncthreads();
    if (*flag) gru_body<float>(cat, bs, Hb, (float*)out, N, sW);
    else       gru_body<short>(cat, bs, Hb, (short*)out, N, sW);
}

extern "C" void kernel_launch(void* const* d_in, const int* in_sizes, int n_in,
                              void* d_out, int out_size, void* d_ws, size_t ws_size,
                              hipStream_t stream) {
    const int E = in_sizes[0] / 2;
    const int N = in_sizes[1] / 128;
    int win = in_sizes[14] / (N * 64); if (win > 8) win = 8;

    char* wp = (char*)d_ws;
    auto alloc = [&](size_t bytes) -> void* {
        void* p = (void*)wp;
        wp += (bytes + 255) & ~(size_t)255;
        return p;
    };
    bf16* bufA = (bf16*)alloc((size_t)N * 128 * 2);
    bf16* bufB = (bf16*)alloc((size_t)N * 128 * 2);
    bf16* Hbf  = (bf16*)alloc((size_t)N * 64 * 2);
    float* xnorm = (float*)alloc((size_t)N * 4);
    int* cnt = (int*)alloc((size_t)N * 4);
    int* fillc = (int*)alloc((size_t)N * 4);
    int* rowptr = (int*)alloc((size_t)(N + 1) * 4);
    float* dis = (float*)alloc((size_t)N * 4);
    int2* edge = (int2*)alloc((size_t)E * 8);
    int* bsum = (int*)alloc((size_t)1025 * 4);
    float* hb1 = (float*)alloc(128 * 4);
    float* y2a = (float*)alloc(256);
    float* hb2 = (float*)alloc(64 * 4);
    float* y2b = (float*)alloc(256);
    float* blf = (float*)alloc(64 * 4);
    float* bs256 = (float*)alloc(256 * 4);
    float* ratf = (float*)alloc(64 * 4);
    short* QT = (short*)alloc(4096 * 2);
    short* Wc = (short*)alloc((size_t)256 * 128 * 2);
    short* Wlb = (short*)alloc((size_t)8192 * 2);
    short* W1b = (short*)alloc((size_t)16384 * 2);
    short* W2b = (short*)alloc((size_t)8192 * 2);
    int* flag = (int*)alloc(256);
    (void)ws_size; (void)out_size; (void)n_in;

    const int* ei = (const int*)d_in[0];

    // ---- cooperative CSR build + dtype detect (1 launch, replaces 7 ops) ----
    {
        const int* srcP = ei;
        const int* dstP = ei + E;
        const void* hidP = d_in[14];
        int Ev = E, Nv = N;
        void* args[] = { (void*)&srcP, (void*)&dstP, (void*)&Ev, (void*)&Nv,
                         (void*)&hidP, (void*)&flag, (void*)&cnt, (void*)&fillc,
                         (void*)&rowptr, (void*)&dis, (void*)&bsum, (void*)&edge };
        hipLaunchCooperativeKernel((void*)k_csr, dim3(1024), dim3(256), args, 0, stream);
    }
    // prep + weight conversion (dtype-branched internally; 1 launch)
    k_prep_all<<<129, 256, 0, stream>>>(d_in[5], d_in[7], d_in[3], d_in[12], d_in[13],
                                        d_in[8], d_in[9], d_in[10], d_in[11],
                                        d_in[2], d_in[4], d_in[6],
                                        hb1, y2a, hb2, y2b, blf, bs256, ratf,
                                        QT, Wc, Wlb, W1b, W2b, flag);
    // HTA window attention: single-pass online-softmax fusion
    k_att<<<(N + 63) / 64, 256, 0, stream>>>(d_in[14], QT, ratf, Hbf, N, win, flag);
    // fused initial linear + toHyperX + concat + conv1 linear
    k_lin0c1<<<(N + 63) / 64, 256, 0, stream>>>(d_in[1], Wlb, blf, d_in[14], win,
                                                W1b, hb1, y2a, bufA, N, flag);
    k_agg2<<<(N + 15) / 16, 256, 0, stream>>>(bufA, rowptr, edge, dis, bufB, xnorm, N);
    // conv2
    k_conv_lin<64><<<(N + 63) / 64, 256, 0, stream>>>(bufB, W2b, hb2, y2b, xnorm, bufB, N);
    k_agg1f<<<(N + 31) / 32, 256, 0, stream>>>(bufB, rowptr, edge, dis, bufA, Hbf, N);
    // GRU fused + toHyperX -> out (output dtype = detected input dtype)
    k_gru<<<(N + 63) / 64, 256, 0, stream>>>(bufA, Wc, bs256, Hbf, d_out, N, flag);
}

// Round 12
// 563.499 us; speedup vs baseline: 1.9891x; 1.9891x over previous
//
#include <hip/hip_runtime.h>
#include <hip/hip_bf16.h>

typedef __hip_bfloat16 bf16;
typedef __attribute__((ext_vector_type(8))) short short8;
typedef __attribute__((ext_vector_type(4))) float f32x4;
typedef __attribute__((ext_vector_type(4))) unsigned u32x4;

#define MAXN 0.996f      // (1 - 4e-3)/sqrt(c), c=1
#define MINN 1e-15f

__device__ __forceinline__ float b2f(short s) {
    union { unsigned u; float f; } c; c.u = ((unsigned)(unsigned short)s) << 16; return c.f;
}
__device__ __forceinline__ short f2b(float f) {   // RNE bf16
    union { float f; unsigned u; } c; c.f = f;
    unsigned r = c.u + 0x7FFF + ((c.u >> 16) & 1);
    return (short)(r >> 16);
}
__device__ __forceinline__ float lo16f(unsigned u) {
    union { unsigned u; float f; } c; c.u = u << 16; return c.f;
}
__device__ __forceinline__ float hi16f(unsigned u) {
    union { unsigned u; float f; } c; c.u = u & 0xFFFF0000u; return c.f;
}
__device__ __forceinline__ unsigned pk2(float x, float y) {
    return (unsigned)(unsigned short)f2b(x) | ((unsigned)(unsigned short)f2b(y) << 16);
}
__device__ __forceinline__ float cv(short v) { return b2f(v); }
__device__ __forceinline__ float cv(float v) { return v; }
__device__ __forceinline__ short tb(short v) { return v; }
__device__ __forceinline__ short tb(float v) { return f2b(v); }
__device__ __forceinline__ short8 ld8(const short* p) { return *(const short8*)p; }
__device__ __forceinline__ short8 ld8(const float* p) {
    float4 a = *(const float4*)p, b = *(const float4*)(p + 4);
    short8 r;
    r[0] = f2b(a.x); r[1] = f2b(a.y); r[2] = f2b(a.z); r[3] = f2b(a.w);
    r[4] = f2b(b.x); r[5] = f2b(b.y); r[6] = f2b(b.z); r[7] = f2b(b.w);
    return r;
}
__device__ __forceinline__ void ldf8(const short* p, float* f) {
    short8 v = *(const short8*)p;
#pragma unroll
    for (int j = 0; j < 8; ++j) f[j] = b2f(v[j]);
}
__device__ __forceinline__ void ldf8(const float* p, float* f) {
    float4 a = *(const float4*)p, b = *(const float4*)(p + 4);
    f[0] = a.x; f[1] = a.y; f[2] = a.z; f[3] = a.w;
    f[4] = b.x; f[5] = b.y; f[6] = b.z; f[7] = b.w;
}
__device__ __forceinline__ void st(short* p, float v) { *p = f2b(v); }
__device__ __forceinline__ void st(float* p, float v) { *p = v; }

__device__ __forceinline__ float red16(float v) {
#pragma unroll
    for (int m = 1; m < 16; m <<= 1) v += __shfl_xor(v, m);
    return v;
}
__device__ __forceinline__ float red8(float v) {
#pragma unroll
    for (int m = 1; m < 8; m <<= 1) v += __shfl_xor(v, m);
    return v;
}

// ---- fast transcendentals (hardware v_exp/v_log/v_rcp; err ~1e-6 rel,
// far below the bf16 quantization of every data buffer) ----
__device__ __forceinline__ float tanh_(float x) {
    float ax = fminf(fabsf(x), 20.f);
    float e = __expf(-2.f * ax);
    float t = (1.f - e) * __builtin_amdgcn_rcpf(1.f + e);
    return copysignf(t, x);
}
__device__ __forceinline__ float artanh_(float x) {
    // callers pass x >= 0 (norms)
    x = fminf(x, 1.f - 1e-7f);
    float x2 = x * x;
    float smal = x * (1.f + x2 * (0.33333334f + x2 * (0.2f + x2 * (0.14285715f + x2 * 0.11111111f))));
    float big = 0.5f * __logf((1.f + x) * __builtin_amdgcn_rcpf(1.f - x));
    return (x < 0.25f) ? smal : big;
}
__device__ __forceinline__ float sigmoidf_(float x) {
    float e = __expf(-x);
    return __builtin_amdgcn_rcpf(1.f + e);
}

// fragment-order index for [DOUT][128] weights: unit ((nt*4+kk)*64+lane), elem e
__device__ __forceinline__ int fragidx(int d, int j) {
    int nt = d >> 4, l15 = d & 15;
    int kk = j >> 5, quad = (j >> 3) & 3, e = j & 7;
    return (((nt << 2) + kk) * 64 + (quad << 4) + l15) * 8 + e;
}

// ---------------- dtype detector: flag=0 bf16, flag=1 f32 ----------------
__global__ void k_detect(const void* hid, int* flag) {
    const short* p = (const short*)hid;
    int t = threadIdx.x;
    int bad = 0;
    for (int i = t; i < 4096; i += 256) {
        unsigned u = (unsigned)(unsigned short)p[i];
        unsigned ex = (u >> 7) & 0xFF;
        if (ex >= 128) bad = 1;   // |v| >= 2 or NaN/Inf -> cannot be in-ball bf16 data
    }
    __shared__ int s;
    if (t == 0) s = 0;
    __syncthreads();
    if (bad) atomicOr(&s, 1);
    __syncthreads();
    if (t == 0) *flag = s;
}

// ---------------- prep body (block 0 of k_prep_all) ----------------
template <typename T>
__device__ void prep_body(const T* b1, const T* b2, const T* bl, const T* bih,
                          const T* bhh, const T* Q, const T* ratt,
                          const T* Wih, const T* Whh,
                          float* hb1, float* y2a, float* hb2, float* y2b,
                          float* blf, float* bs256, float* ratf,
                          short* QT, short* Wc, float* sb) {
    int t = threadIdx.x;
    float v1 = (t < 128) ? cv(b1[t]) : 0.f;
    sb[t] = v1 * v1; __syncthreads();
    for (int d = 128; d > 0; d >>= 1) { if (t < d) sb[t] += sb[t + d]; __syncthreads(); }
    float n2a = sb[0]; __syncthreads();
    {
        float un = fmaxf(sqrtf(n2a), MINN);
        float e = tanh_(un), tt = e / un;
        float s = (e > MAXN) ? MAXN / e : 1.f;
        if (t < 128) hb1[t] = s * tt * v1;
        if (t == 0) { float hn = s * e; y2a[0] = hn * hn; }
    }
    float v2 = (t < 64) ? cv(b2[t]) : 0.f;
    sb[t] = v2 * v2; __syncthreads();
    for (int d = 128; d > 0; d >>= 1) { if (t < d) sb[t] += sb[t + d]; __syncthreads(); }
    float n2b = sb[0]; __syncthreads();
    {
        float un = fmaxf(sqrtf(n2b), MINN);
        float e = tanh_(un), tt = e / un;
        float s = (e > MAXN) ? MAXN / e : 1.f;
        if (t < 64) hb2[t] = s * tt * v2;
        if (t == 0) { float hn = s * e; y2b[0] = hn * hn; }
    }
    for (int i = t; i < 64; i += 256) {
        blf[i] = cv(bl[i]);
        ratf[i] = cv(ratt[i]);
    }
    {
        float v = (t < 192) ? (cv(bih[t]) + cv(bhh[t])) : cv(bhh[t - 64]);
        bs256[t] = v;
    }
    for (int i = t; i < 4096; i += 256) { int k = i >> 6, n = i & 63; QT[n * 64 + k] = tb(Q[k * 64 + n]); }
    // GRU combined weight in MFMA-fragment order
    for (int i = t; i < 256 * 128; i += 256) {
        int d = i >> 7, j = i & 127;
        short v;
        if (d < 192) v = (j < 64) ? tb(Wih[d * 64 + j]) : tb(Whh[d * 64 + (j - 64)]);
        else         v = (j < 64) ? (short)0 : tb(Whh[(d - 64) * 64 + (j - 64)]);
        Wc[fragidx(d, j)] = v;
    }
}

template <typename T>
__device__ void wcvt_body(int i, const T* Wl, const T* W1, const T* W2,
                          short* Wlb, short* W1b, short* W2b) {
    if (i < 8192) {
        Wlb[fragidx(i >> 7, i & 127)] = tb(Wl[i]);
    } else if (i < 24576) {
        int i2 = i - 8192;
        W1b[fragidx(i2 >> 7, i2 & 127)] = tb(W1[i2]);
    } else if (i < 32768) {
        int i2 = i - 24576;
        W2b[fragidx(i2 >> 7, i2 & 127)] = tb(W2[i2]);
    }
}

// prep + weight conversion, dtype-branched internally. Launch 129 blocks.
__global__ __launch_bounds__(256) void k_prep_all(
        const void* b1, const void* b2, const void* bl, const void* bih,
        const void* bhh, const void* Q, const void* ratt,
        const void* Wih, const void* Whh,
        const void* Wl, const void* W1, const void* W2,
        float* hb1, float* y2a, float* hb2, float* y2b,
        float* blf, float* bs256, float* ratf,
        short* QT, short* Wc,
        short* Wlb, short* W1b, short* W2b, const int* flag) {
    __shared__ float sb[256];
    int f = *flag;
    if (blockIdx.x == 0) {
        if (f) prep_body<float>((const float*)b1, (const float*)b2, (const float*)bl,
                                (const float*)bih, (const float*)bhh, (const float*)Q,
                                (const float*)ratt, (const float*)Wih, (const float*)Whh,
                                hb1, y2a, hb2, y2b, blf, bs256, ratf, QT, Wc, sb);
        else   prep_body<short>((const short*)b1, (const short*)b2, (const short*)bl,
                                (const short*)bih, (const short*)bhh, (const short*)Q,
                                (const short*)ratt, (const short*)Wih, (const short*)Whh,
                                hb1, y2a, hb2, y2b, blf, bs256, ratf, QT, Wc, sb);
    } else {
        int i = (blockIdx.x - 1) * 256 + threadIdx.x;
        if (f) wcvt_body<float>(i, (const float*)Wl, (const float*)W1, (const float*)W2, Wlb, W1b, W2b);
        else   wcvt_body<short>(i, (const short*)Wl, (const short*)W1, (const short*)W2, Wlb, W1b, W2b);
    }
}

// ---------------- CSR ----------------
__global__ void k_count(const int* __restrict__ src, int E, int* __restrict__ cnt) {
    int i = blockIdx.x * blockDim.x + threadIdx.x;
    if (i < E) atomicAdd(&cnt[src[i]], 1);
}

// ---- multi-block exclusive scan ----
#define SC_CHUNK 2048
__global__ __launch_bounds__(256) void k_scan_bsum(const int* __restrict__ cnt, int N,
                                                   int* __restrict__ bsum) {
    __shared__ int sb[256];
    int t = threadIdx.x;
    int base = blockIdx.x * SC_CHUNK + t * 8;
    int s = 0;
#pragma unroll
    for (int j = 0; j < 8; ++j) { int i = base + j; if (i < N) s += cnt[i]; }
    sb[t] = s; __syncthreads();
    for (int d = 128; d > 0; d >>= 1) { if (t < d) sb[t] += sb[t + d]; __syncthreads(); }
    if (t == 0) bsum[blockIdx.x] = sb[0];
}
__global__ __launch_bounds__(1024) void k_scan_bpre(int* __restrict__ bsum, int nb) {
    __shared__ int sb[1024];
    int t = threadIdx.x;
    sb[t] = (t < nb) ? bsum[t] : 0;
    __syncthreads();
    for (int d = 1; d < 1024; d <<= 1) {
        int u = (t >= d) ? sb[t - d] : 0; __syncthreads();
        sb[t] += u; __syncthreads();
    }
    if (t < nb) bsum[t] = (t == 0) ? 0 : sb[t - 1];
    if (t == 0) bsum[nb] = sb[1023];
}
// scan_write also emits dis[i] = 1/sqrt(deg+1)  (fused former k_dis)
__global__ __launch_bounds__(256) void k_scan_write(const int* __restrict__ cnt,
                                                    int* __restrict__ rowptr, int N,
                                                    const int* __restrict__ bsum, int nb,
                                                    float* __restrict__ dis) {
    __shared__ int sb[256];
    int t = threadIdx.x;
    int b = blockIdx.x;
    int base = b * SC_CHUNK + t * 8;
    int v[8]; int s = 0;
#pragma unroll
    for (int j = 0; j < 8; ++j) { int i = base + j; v[j] = (i < N) ? cnt[i] : 0; s += v[j]; }
    sb[t] = s; __syncthreads();
    for (int d = 1; d < 256; d <<= 1) {
        int u = (t >= d) ? sb[t - d] : 0; __syncthreads();
        sb[t] += u; __syncthreads();
    }
    int run = bsum[b] + ((t == 0) ? 0 : sb[t - 1]);
#pragma unroll
    for (int j = 0; j < 8; ++j) {
        int i = base + j;
        if (i < N) {
            rowptr[i] = run;
            dis[i] = 1.f / sqrtf((float)(v[j] + 1));
        }
        run += v[j];
    }
    if (b == 0 && t == 0) rowptr[N] = bsum[nb];
}

// fill writes interleaved edge records {col, weight} (weight = dis[s]*dis[d])
__global__ void k_fill(const int* __restrict__ src, const int* __restrict__ dst, int E,
                       const int* __restrict__ rowptr, int* __restrict__ fill,
                       int2* __restrict__ edge, const float* __restrict__ dis) {
    int i = blockIdx.x * blockDim.x + threadIdx.x;
    if (i < E) {
        int s = src[i], d = dst[i];
        int p = rowptr[s] + atomicAdd(&fill[s], 1);
        int2 e; e.x = d; e.y = __float_as_int(dis[s] * dis[d]);
        edge[p] = e;
    }
}

// --------- fused HTA attention: logmap0 -> scores -> ONLINE softmax -> combine ----
template <typename T>
__device__ void att_body(const T* hid, const short* QT, const float* ratf,
                         bf16* Hb, int N, int win) {
    int wid = threadIdx.x >> 6, lane = threadIdx.x & 63;
    int row0 = blockIdx.x * 64 + wid * 16;
    if (row0 >= N) return;
    int l15 = lane & 15, quad = lane >> 4;
    int node = row0 + l15;
    int nodeC = (node < N) ? node : (N - 1);
    // hoisted QT fragments (loop-invariant)
    short8 qb0[4], qb1[4];
    float rw[4];
#pragma unroll
    for (int nt = 0; nt < 4; ++nt) {
        qb0[nt] = *(const short8*)(QT + (size_t)(nt * 16 + l15) * 64 + quad * 8);
        qb1[nt] = *(const short8*)(QT + (size_t)(nt * 16 + l15) * 64 + 32 + quad * 8);
        rw[nt] = ratf[nt * 16 + l15];
    }
    float m = -1e30f, srun = 0.f;
    float h[16];
#pragma unroll
    for (int j = 0; j < 16; ++j) h[j] = 0.f;
    for (int w = 0; w < win; ++w) {
        const T* Hrow = hid + ((size_t)w * N + nodeC) * 64 + quad * 8;
        float f0[8], f1[8];
        ldf8(Hrow, f0); ldf8(Hrow + 32, f1);
        float sq = 0.f;
#pragma unroll
        for (int j = 0; j < 8; ++j) sq += f0[j] * f0[j] + f1[j] * f1[j];
        sq += __shfl_xor(sq, 16); sq += __shfl_xor(sq, 32);
        float pn = fmaxf(sqrtf(sq), MINN);
        float lt = artanh_(pn) / pn;
        short8 s0, s1;
#pragma unroll
        for (int j = 0; j < 8; ++j) { s0[j] = f2b(lt * f0[j]); s1[j] = f2b(lt * f1[j]); }
        f32x4 acc[4];
#pragma unroll
        for (int nt = 0; nt < 4; ++nt) acc[nt] = (f32x4){0.f, 0.f, 0.f, 0.f};
#pragma unroll
        for (int nt = 0; nt < 4; ++nt) {
            acc[nt] = __builtin_amdgcn_mfma_f32_16x16x32_bf16(s0, qb0[nt], acc[nt], 0, 0, 0);
            acc[nt] = __builtin_amdgcn_mfma_f32_16x16x32_bf16(s1, qb1[nt], acc[nt], 0, 0, 0);
        }
        float er[4];
#pragma unroll
        for (int r = 0; r < 4; ++r) {
            float s = 0.f;
#pragma unroll
            for (int nt = 0; nt < 4; ++nt) s += tanh_(acc[nt][r]) * rw[nt];
            er[r] = red16(s);       // all lanes of this quad hold E[row0+quad*4+r]
        }
        // broadcast: this lane needs E of node row0+l15 (held by quad l15>>2, slot l15&3)
        int srcLane = (l15 >> 2) << 4;
        float t0 = __shfl(er[0], srcLane);
        float t1 = __shfl(er[1], srcLane);
        float t2 = __shfl(er[2], srcLane);
        float t3 = __shfl(er[3], srcLane);
        int rr = l15 & 3;
        float Eval = (rr == 0) ? t0 : (rr == 1) ? t1 : (rr == 2) ? t2 : t3;
        // online softmax update
        float mn = fmaxf(m, Eval);
        float c = __expf(m - mn);
        float p = __expf(Eval - mn);
        m = mn;
        srun = srun * c + p;
#pragma unroll
        for (int j = 0; j < 8; ++j) {
            h[j]     = h[j]     * c + p * (lt * f0[j]);
            h[8 + j] = h[8 + j] * c + p * (lt * f1[j]);
        }
    }
    if (node < N) {
        float den = srun * (float)win;
        short8 o0, o1;
#pragma unroll
        for (int j = 0; j < 8; ++j) { o0[j] = f2b(h[j] / den); o1[j] = f2b(h[8 + j] / den); }
        *(short8*)((short*)Hb + (size_t)node * 64 + quad * 8) = o0;
        *(short8*)((short*)Hb + (size_t)node * 64 + 32 + quad * 8) = o1;
    }
}
__global__ __launch_bounds__(256) void k_att(const void* hid, const short* __restrict__ QT,
                                             const float* __restrict__ ratf,
                                             bf16* __restrict__ Hb, int N, int win, const int* flag) {
    if (*flag) att_body<float>((const float*)hid, QT, ratf, Hb, N, win);
    else       att_body<short>((const short*)hid, QT, ratf, Hb, N, win);
}

// --------- FUSED: initial linear + toHyperX + concat -> (LDS) -> conv1 linear ----
#define SXSTR 136
template <typename T>
__device__ void lin0c1_body(const T* feat, const short* Wl, const float* blf, const T* hid,
                            int win, const short* W1, const float* hb1, const float* y2p,
                            bf16* outA, int N, short* sX) {
    int t = threadIdx.x;
    int wid = t >> 6, lane = t & 63;
    int row0 = blockIdx.x * 64 + wid * 16;
    if (row0 >= N) return;
    int l15 = lane & 15, quad = lane >> 4;
    short* sx = sX + wid * 16 * SXSTR;     // this wave's 16x128 tile (padded)
    // ---- phase 1: lin0 GEMM (feat @ Wl^T) ----
    const short8* Wf = (const short8*)Wl;
    f32x4 acc[4];
#pragma unroll
    for (int nt = 0; nt < 4; ++nt) acc[nt] = (f32x4){0.f, 0.f, 0.f, 0.f};
    const T* Arow = feat + (size_t)(row0 + l15) * 128 + quad * 8;
#pragma unroll
    for (int kk = 0; kk < 4; ++kk) {
        short8 a = ld8(Arow + kk * 32);
#pragma unroll
        for (int nt = 0; nt < 4; ++nt) {
            short8 b = Wf[(nt * 4 + kk) * 64 + lane];
            acc[nt] = __builtin_amdgcn_mfma_f32_16x16x32_bf16(a, b, acc[nt], 0, 0, 0);
        }
    }
    float bv[4];
#pragma unroll
    for (int nt = 0; nt < 4; ++nt) bv[nt] = blf[nt * 16 + l15];
    float xn_r[4];
#pragma unroll
    for (int r = 0; r < 4; ++r) {
        int row = row0 + quad * 4 + r;
        float g[4], u2 = 0.f;
#pragma unroll
        for (int nt = 0; nt < 4; ++nt) { g[nt] = acc[nt][r] + bv[nt]; u2 += g[nt] * g[nt]; }
        u2 = red16(u2);
        float un = fmaxf(sqrtf(u2), MINN);
        float e = tanh_(un), tt = e / un;
        float s1 = (e > MAXN) ? MAXN / e : 1.f;
        float x0n = s1 * e;
        float hv[4], h2 = 0.f;
#pragma unroll
        for (int nt = 0; nt < 4; ++nt) {
            hv[nt] = cv(hid[((size_t)(win - 1) * N + row) * 64 + nt * 16 + l15]);
            h2 += hv[nt] * hv[nt];
        }
        h2 = red16(h2);
        float n128 = sqrtf(x0n * x0n + h2);
        float s2 = (n128 > MAXN) ? MAXN / n128 : 1.f;
        short* srow = sx + (quad * 4 + r) * SXSTR;
#pragma unroll
        for (int nt = 0; nt < 4; ++nt) {
            srow[nt * 16 + l15] = f2b(s2 * s1 * tt * g[nt]);
            srow[64 + nt * 16 + l15] = f2b(s2 * hv[nt]);
        }
        xn_r[r] = fmaxf(fminf(n128, MAXN), MINN);
    }
    // ---- phase 2: conv1 GEMM from LDS (wave-internal dep; no barrier) ----
    const short8* W1f = (const short8*)W1;
    f32x4 acc2[8];
#pragma unroll
    for (int nt = 0; nt < 8; ++nt) acc2[nt] = (f32x4){0.f, 0.f, 0.f, 0.f};
    const short* Ax = sx + l15 * SXSTR + quad * 8;
#pragma unroll
    for (int kk = 0; kk < 4; ++kk) {
        short8 a = *(const short8*)(Ax + kk * 32);
#pragma unroll
        for (int nt = 0; nt < 8; ++nt) {
            short8 b = W1f[(nt * 4 + kk) * 64 + lane];
            acc2[nt] = __builtin_amdgcn_mfma_f32_16x16x32_bf16(a, b, acc2[nt], 0, 0, 0);
        }
    }
    float y2 = y2p[0];
    float hbv[8];
#pragma unroll
    for (int nt = 0; nt < 8; ++nt) hbv[nt] = hb1[nt * 16 + l15];
#pragma unroll
    for (int r = 0; r < 4; ++r) {
        int row = row0 + quad * 4 + r;
        float mx[8], m2 = 0.f;
#pragma unroll
        for (int nt = 0; nt < 8; ++nt) { mx[nt] = acc2[nt][r]; m2 += mx[nt] * mx[nt]; }
        m2 = red16(m2);
        float mxn = fmaxf(sqrtf(m2), MINN);
        float xn = xn_r[r];
        float at = artanh_(xn);
        float f = (m2 == 0.f) ? 0.f : tanh_(mxn / xn * at) / mxn;
        float rn = f * mxn;
        float s1 = (rn > MAXN) ? MAXN / rn : 1.f;
        float a_ = s1 * f, mvn = s1 * rn;
        float x2 = mvn * mvn;
        float xy = 0.f;
#pragma unroll
        for (int nt = 0; nt < 8; ++nt) xy += (a_ * mx[nt]) * hbv[nt];
        xy = red16(xy);
        float co = 1.f + 2.f * xy + y2, cx = 1.f - x2;
        float den = fmaxf(1.f + 2.f * xy + x2 * y2, MINN);
        float o[8], on2 = 0.f;
#pragma unroll
        for (int nt = 0; nt < 8; ++nt) { o[nt] = (co * a_ * mx[nt] + cx * hbv[nt]) / den; on2 += o[nt] * o[nt]; }
        on2 = red16(on2);
        float on = sqrtf(on2);
        float s3 = (on > MAXN) ? MAXN / on : 1.f;
        float hn = fmaxf(s3 * on, MINN);
        float lt = artanh_(hn) / hn;
#pragma unroll
        for (int nt = 0; nt < 8; ++nt)
            ((short*)outA)[(size_t)row * 128 + nt * 16 + l15] = f2b(lt * s3 * o[nt]);
    }
}
__global__ __launch_bounds__(256) void k_lin0c1(const void* feat, const short* __restrict__ Wl,
                                                const float* __restrict__ blf, const void* hid,
                                                int win, const short* __restrict__ W1,
                                                const float* __restrict__ hb1, const float* __restrict__ y2a,
                                                bf16* __restrict__ outA, int N, const int* flag) {
    __shared__ short sX[4 * 16 * SXSTR];   // 17408 B
    if (*flag) lin0c1_body<float>((const float*)feat, Wl, blf, (const float*)hid, win, W1, hb1, y2a, outA, N, sX);
    else       lin0c1_body<short>((const short*)feat, Wl, blf, (const short*)hid, win, W1, hb1, y2a, outA, N, sX);
}

// ------- conv2 linear: GEMM fused with matvec->proj->madd(hb)->proj->logmap0 ----
template <int DOUT>
__global__ __launch_bounds__(256) void k_conv_lin(const bf16* __restrict__ in, const short* __restrict__ W,
                                                  const float* __restrict__ hb, const float* __restrict__ y2p,
                                                  const float* __restrict__ xnorm,
                                                  bf16* __restrict__ out, int N) {
    constexpr int NT = DOUT / 16;
    int t = threadIdx.x;
    int wid = t >> 6, lane = t & 63;
    int row0 = blockIdx.x * 64 + wid * 16;
    if (row0 >= N) return;
    int l15 = lane & 15, quad = lane >> 4;
    const short8* Wf = (const short8*)W;
    f32x4 acc[NT];
#pragma unroll
    for (int nt = 0; nt < NT; ++nt) acc[nt] = (f32x4){0.f, 0.f, 0.f, 0.f};
    const short* Arow = (const short*)in + (size_t)(row0 + l15) * 128 + quad * 8;
#pragma unroll
    for (int kk = 0; kk < 4; ++kk) {
        short8 a = *(const short8*)(Arow + kk * 32);
#pragma unroll
        for (int nt = 0; nt < NT; ++nt) {
            short8 b = Wf[(nt * 4 + kk) * 64 + lane];
            acc[nt] = __builtin_amdgcn_mfma_f32_16x16x32_bf16(a, b, acc[nt], 0, 0, 0);
        }
    }
    float y2 = y2p[0];
    float hbv[NT];
#pragma unroll
    for (int nt = 0; nt < NT; ++nt) hbv[nt] = hb[nt * 16 + l15];
#pragma unroll
    for (int r = 0; r < 4; ++r) {
        int row = row0 + quad * 4 + r;
        float mx[NT], m2 = 0.f;
#pragma unroll
        for (int nt = 0; nt < NT; ++nt) { mx[nt] = acc[nt][r]; m2 += mx[nt] * mx[nt]; }
        m2 = red16(m2);
        float mxn = fmaxf(sqrtf(m2), MINN);
        float xn = xnorm[row];
        float at = artanh_(xn);
        float f = (m2 == 0.f) ? 0.f : tanh_(mxn / xn * at) / mxn;
        float rn = f * mxn;
        float s1 = (rn > MAXN) ? MAXN / rn : 1.f;
        float a_ = s1 * f, mvn = s1 * rn;
        float x2 = mvn * mvn;
        float xy = 0.f;
#pragma unroll
        for (int nt = 0; nt < NT; ++nt) xy += (a_ * mx[nt]) * hbv[nt];
        xy = red16(xy);
        float co = 1.f + 2.f * xy + y2, cx = 1.f - x2;
        float den = fmaxf(1.f + 2.f * xy + x2 * y2, MINN);
        float o[NT], on2 = 0.f;
#pragma unroll
        for (int nt = 0; nt < NT; ++nt) { o[nt] = (co * a_ * mx[nt] + cx * hbv[nt]) / den; on2 += o[nt] * o[nt]; }
        on2 = red16(on2);
        float on = sqrtf(on2);
        float s3 = (on > MAXN) ? MAXN / on : 1.f;
        float hn = fmaxf(s3 * on, MINN);
        float lt = artanh_(hn) / hn;
#pragma unroll
        for (int nt = 0; nt < NT; ++nt)
            ((short*)out)[(size_t)row * 128 + nt * 16 + l15] = f2b(lt * s3 * o[nt]);
    }
}

// --------- agg (conv1, D=128): 4 nodes/wave, 16 lanes/node, dwordx4 -------
__global__ __launch_bounds__(256) void k_agg2(const bf16* __restrict__ xt, const int* __restrict__ rowptr,
                                              const int2* __restrict__ edge,
                                              const float* __restrict__ dis,
                                              bf16* __restrict__ out, float* __restrict__ xnorm, int N) {
    int wid = threadIdx.x >> 6, lane = threadIdx.x & 63;
    int g = lane >> 4, l15 = lane & 15;
    int i = blockIdx.x * 16 + wid * 4 + g;
    bool act = (i < N);
    int ii = act ? i : (N - 1);
    const u32x4* xq = (const u32x4*)xt;            // 16 u32x4 per 128-feat row
    float di = dis[ii];
    float w0 = di * di;
    u32x4 d0 = xq[(size_t)ii * 16 + l15];
    float a[8];
#pragma unroll
    for (int k = 0; k < 4; ++k) { a[2 * k] = w0 * lo16f(d0[k]); a[2 * k + 1] = w0 * hi16f(d0[k]); }
    int e0 = rowptr[ii], e1 = act ? rowptr[ii + 1] : e0;
    for (int j = e0; j < e1; ++j) {
        int2 e = edge[j];
        float w = __int_as_float(e.y);
        u32x4 d = xq[(size_t)e.x * 16 + l15];
#pragma unroll
        for (int k = 0; k < 4; ++k) { a[2 * k] += w * lo16f(d[k]); a[2 * k + 1] += w * hi16f(d[k]); }
    }
    float sq = 0.f;
#pragma unroll
    for (int k = 0; k < 8; ++k) sq += a[k] * a[k];
    float an = fmaxf(sqrtf(red16(sq)), MINN);
    float e1t = tanh_(an), t1 = e1t / an;
    float s1 = (e1t > MAXN) ? MAXN / e1t : 1.f;
    float hn = fmaxf(s1 * e1t, MINN);
    float lt = artanh_(hn) / hn;
    float sht = s1 * t1 * lt;
    float v[8], v2 = 0.f;
#pragma unroll
    for (int k = 0; k < 8; ++k) {
        float t = sht * a[k];
        t = (t >= 0.f) ? t : 0.01f * t;
        v[k] = t; v2 += t * t;
    }
    float tn = fmaxf(sqrtf(red16(v2)), MINN);
    float e2 = tanh_(tn), t2 = e2 / tn;
    float s2 = (e2 > MAXN) ? MAXN / e2 : 1.f;
    float sc = s2 * t2;
    if (act) {
        u32x4 o;
#pragma unroll
        for (int k = 0; k < 4; ++k) o[k] = pk2(sc * v[2 * k], sc * v[2 * k + 1]);
        ((u32x4*)out)[(size_t)i * 16 + l15] = o;
        if (l15 == 0) xnorm[i] = fmaxf(fminf(e2, MAXN), MINN);
    }
}

// --------- agg (conv2, D=64) + FINAL logmap0: 8 nodes/wave, 8 lanes/node --
__global__ __launch_bounds__(256) void k_agg1f(const bf16* __restrict__ xt, const int* __restrict__ rowptr,
                                               const int2* __restrict__ edge,
                                               const float* __restrict__ dis,
                                               bf16* __restrict__ out, const bf16* __restrict__ Hb, int N) {
    int wid = threadIdx.x >> 6, lane = threadIdx.x & 63;
    int g = lane >> 3, l7 = lane & 7;
    int i = blockIdx.x * 32 + wid * 8 + g;
    bool act = (i < N);
    int ii = act ? i : (N - 1);
    const u32x4* xq = (const u32x4*)xt;            // row stride 16 u32x4; feats = first 8
    float di = dis[ii];
    float w0 = di * di;
    u32x4 d0 = xq[(size_t)ii * 16 + l7];
    float a[8];
#pragma unroll
    for (int k = 0; k < 4; ++k) { a[2 * k] = w0 * lo16f(d0[k]); a[2 * k + 1] = w0 * hi16f(d0[k]); }
    int e0 = rowptr[ii], e1 = act ? rowptr[ii + 1] : e0;
    for (int j = e0; j < e1; ++j) {
        int2 e = edge[j];
        float w = __int_as_float(e.y);
        u32x4 d = xq[(size_t)e.x * 16 + l7];
#pragma unroll
        for (int k = 0; k < 4; ++k) { a[2 * k] += w * lo16f(d[k]); a[2 * k + 1] += w * hi16f(d[k]); }
    }
    float sq = 0.f;
#pragma unroll
    for (int k = 0; k < 8; ++k) sq += a[k] * a[k];
    float an = fmaxf(sqrtf(red8(sq)), MINN);
    float e1t = tanh_(an), t1 = e1t / an;
    float s1 = (e1t > MAXN) ? MAXN / e1t : 1.f;
    float hn = fmaxf(s1 * e1t, MINN);
    float lt = artanh_(hn) / hn;
    float sht = s1 * t1 * lt;
    float v[8], v2 = 0.f;
#pragma unroll
    for (int k = 0; k < 8; ++k) {
        float t = sht * a[k];
        t = (t >= 0.f) ? t : 0.01f * t;
        v[k] = t; v2 += t * t;
    }
    float tn = fmaxf(sqrtf(red8(v2)), MINN);
    float e2 = tanh_(tn), t2 = e2 / tn;
    float s2 = (e2 > MAXN) ? MAXN / e2 : 1.f;
    float sc = s2 * t2;
    float xnf = fmaxf(fminf(s2 * e2, MAXN), MINN);
    float lt2 = artanh_(xnf) / xnf;
    sc *= lt2;
    if (act) {
        u32x4 o;
#pragma unroll
        for (int k = 0; k < 4; ++k) o[k] = pk2(sc * v[2 * k], sc * v[2 * k + 1]);
        u32x4* od = (u32x4*)out;
        od[(size_t)i * 16 + l7] = o;
        od[(size_t)i * 16 + 8 + l7] = ((const u32x4*)Hb)[(size_t)i * 8 + l7];
    }
}

// --------- GRU fused + expmap0/proj -> out (dtype-branched) -----
template <typename OT>
__device__ void gru_body(const bf16* cat, const float* bs, const bf16* Hb,
                         OT* out, int N, const short8* sW) {
    int t = threadIdx.x;
    int wid = t >> 6, lane = t & 63;
    int row0 = blockIdx.x * 64 + wid * 16;
    if (row0 >= N) return;
    int l15 = lane & 15, quad = lane >> 4;
    f32x4 acc[16];
#pragma unroll
    for (int nt = 0; nt < 16; ++nt) acc[nt] = (f32x4){0.f, 0.f, 0.f, 0.f};
    const short* Arow = (const short*)cat + (size_t)(row0 + l15) * 128 + quad * 8;
#pragma unroll
    for (int kk = 0; kk < 4; ++kk) {
        short8 a = *(const short8*)(Arow + kk * 32);
#pragma unroll
        for (int nt = 0; nt < 16; ++nt) {
            short8 b = sW[(nt * 4 + kk) * 64 + lane];
            acc[nt] = __builtin_amdgcn_mfma_f32_16x16x32_bf16(a, b, acc[nt], 0, 0, 0);
        }
    }
#pragma unroll
    for (int r = 0; r < 4; ++r) {
        int row = row0 + quad * 4 + r;
        float zv[4], z2 = 0.f;
#pragma unroll
        for (int nt = 0; nt < 4; ++nt) {
            int c = nt * 16 + l15;
            float gr = acc[nt][r] + bs[c];
            float gz = acc[nt + 4][r] + bs[c + 64];
            float gn = acc[nt + 8][r] + bs[c + 128];
            float hn = acc[nt + 12][r] + bs[c + 192];
            float hv = b2f(((const short*)Hb)[(size_t)row * 64 + c]);
            float rr = sigmoidf_(gr), zz = sigmoidf_(gz);
            float nn = tanh_(gn + (rr - 1.f) * hn);
            zv[nt] = (1.f - zz) * nn + zz * hv;
            z2 += zv[nt] * zv[nt];
        }
        z2 = red16(z2);
        float un = fmaxf(sqrtf(z2), MINN);
        float e = tanh_(un), tt = e / un;
        float s = (e > MAXN) ? MAXN / e : 1.f;
#pragma unroll
        for (int nt = 0; nt < 4; ++nt)
            st(&out[(size_t)row * 64 + nt * 16 + l15], s * tt * zv[nt]);
    }
}
__global__ __launch_bounds__(256) void k_gru(const bf16* __restrict__ cat, const short* __restrict__ Wc,
                                             const float* __restrict__ bs, const bf16* __restrict__ Hb,
                                             void* out, int N, const int* flag) {
    __shared__ short8 sW[4096];        // 64KB: 256x128 bf16, single allocation for both paths
    int t = threadIdx.x;
#pragma unroll
    for (int u = 0; u < 16; ++u) sW[u * 256 + t] = ((const short8*)Wc)[u * 256 + t];
    __syncthreads();
    if (*flag) gru_body<float>(cat, bs, Hb, (float*)out, N, sW);
    else       gru_body<short>(cat, bs, Hb, (short*)out, N, sW);
}

extern "C" void kernel_launch(void* const* d_in, const int* in_sizes, int n_in,
                              void* d_out, int out_size, void* d_ws, size_t ws_size,
                              hipStream_t stream) {
    const int E = in_sizes[0] / 2;
    const int N = in_sizes[1] / 128;
    int win = in_sizes[14] / (N * 64); if (win > 8) win = 8;

    char* wp = (char*)d_ws;
    auto alloc = [&](size_t bytes) -> void* {
        void* p = (void*)wp;
        wp += (bytes + 255) & ~(size_t)255;
        return p;
    };
    bf16* bufA = (bf16*)alloc((size_t)N * 128 * 2);
    bf16* bufB = (bf16*)alloc((size_t)N * 128 * 2);
    bf16* Hbf  = (bf16*)alloc((size_t)N * 64 * 2);
    float* xnorm = (float*)alloc((size_t)N * 4);
    int* cnt = (int*)alloc((size_t)N * 4);
    int* fillc = (int*)alloc((size_t)N * 4);
    int* rowptr = (int*)alloc((size_t)(N + 1) * 4);
    float* dis = (float*)alloc((size_t)N * 4);
    int2* edge = (int2*)alloc((size_t)E * 8);
    int* bsum = (int*)alloc((size_t)1025 * 4);
    float* hb1 = (float*)alloc(128 * 4);
    float* y2a = (float*)alloc(256);
    float* hb2 = (float*)alloc(64 * 4);
    float* y2b = (float*)alloc(256);
    float* blf = (float*)alloc(64 * 4);
    float* bs256 = (float*)alloc(256 * 4);
    float* ratf = (float*)alloc(64 * 4);
    short* QT = (short*)alloc(4096 * 2);
    short* Wc = (short*)alloc((size_t)256 * 128 * 2);
    short* Wlb = (short*)alloc((size_t)8192 * 2);
    short* W1b = (short*)alloc((size_t)16384 * 2);
    short* W2b = (short*)alloc((size_t)8192 * 2);
    int* flag = (int*)alloc(256);
    (void)ws_size; (void)out_size; (void)n_in;

    const int* ei = (const int*)d_in[0];

    k_detect<<<1, 256, 0, stream>>>(d_in[14], flag);

    // prep + weight conversion (dtype-branched internally; 1 launch)
    k_prep_all<<<129, 256, 0, stream>>>(d_in[5], d_in[7], d_in[3], d_in[12], d_in[13],
                                        d_in[8], d_in[9], d_in[10], d_in[11],
                                        d_in[2], d_in[4], d_in[6],
                                        hb1, y2a, hb2, y2b, blf, bs256, ratf,
                                        QT, Wc, Wlb, W1b, W2b, flag);
    // CSR build (dtype-free); cnt+fillc zeroed by one async memset (adjacent allocs)
    {
        size_t cntPad = ((size_t)N * 4 + 255) & ~(size_t)255;
        hipMemsetAsync(cnt, 0, cntPad + (size_t)N * 4, stream);
    }
    k_count<<<(E + 255) / 256, 256, 0, stream>>>(ei, E, cnt);
    {
        int nb = (N + SC_CHUNK - 1) / SC_CHUNK;   // <=1024 for N<=2M
        k_scan_bsum<<<nb, 256, 0, stream>>>(cnt, N, bsum);
        k_scan_bpre<<<1, 1024, 0, stream>>>(bsum, nb);
        k_scan_write<<<nb, 256, 0, stream>>>(cnt, rowptr, N, bsum, nb, dis);
    }
    k_fill<<<(E + 255) / 256, 256, 0, stream>>>(ei, ei + E, E, rowptr, fillc, edge, dis);
    // HTA window attention: single-pass online-softmax fusion
    k_att<<<(N + 63) / 64, 256, 0, stream>>>(d_in[14], QT, ratf, Hbf, N, win, flag);
    // fused initial linear + toHyperX + concat + conv1 linear
    k_lin0c1<<<(N + 63) / 64, 256, 0, stream>>>(d_in[1], Wlb, blf, d_in[14], win,
                                                W1b, hb1, y2a, bufA, N, flag);
    k_agg2<<<(N + 15) / 16, 256, 0, stream>>>(bufA, rowptr, edge, dis, bufB, xnorm, N);
    // conv2
    k_conv_lin<64><<<(N + 63) / 64, 256, 0, stream>>>(bufB, W2b, hb2, y2b, xnorm, bufB, N);
    k_agg1f<<<(N + 31) / 32, 256, 0, stream>>>(bufB, rowptr, edge, dis, bufA, Hbf, N);
    // GRU fused + toHyperX -> out (output dtype = detected input dtype)
    k_gru<<<(N + 63) / 64, 256, 0, stream>>>(bufA, Wc, bs256, Hbf, d_out, N, flag);
}

// Round 13
// 547.227 us; speedup vs baseline: 2.0482x; 1.0297x over previous
//
#include <hip/hip_runtime.h>
#include <hip/hip_bf16.h>

typedef __hip_bfloat16 bf16;
typedef __attribute__((ext_vector_type(8))) short short8;
typedef __attribute__((ext_vector_type(4))) float f32x4;
typedef __attribute__((ext_vector_type(4))) unsigned u32x4;

#define MAXN 0.996f      // (1 - 4e-3)/sqrt(c), c=1
#define MINN 1e-15f

__device__ __forceinline__ float b2f(short s) {
    union { unsigned u; float f; } c; c.u = ((unsigned)(unsigned short)s) << 16; return c.f;
}
__device__ __forceinline__ short f2b(float f) {   // RNE bf16
    union { float f; unsigned u; } c; c.f = f;
    unsigned r = c.u + 0x7FFF + ((c.u >> 16) & 1);
    return (short)(r >> 16);
}
__device__ __forceinline__ float lo16f(unsigned u) {
    union { unsigned u; float f; } c; c.u = u << 16; return c.f;
}
__device__ __forceinline__ float hi16f(unsigned u) {
    union { unsigned u; float f; } c; c.u = u & 0xFFFF0000u; return c.f;
}
__device__ __forceinline__ unsigned pk2(float x, float y) {
    return (unsigned)(unsigned short)f2b(x) | ((unsigned)(unsigned short)f2b(y) << 16);
}
__device__ __forceinline__ float cv(short v) { return b2f(v); }
__device__ __forceinline__ float cv(float v) { return v; }
__device__ __forceinline__ short tb(short v) { return v; }
__device__ __forceinline__ short tb(float v) { return f2b(v); }
__device__ __forceinline__ short8 ld8(const short* p) { return *(const short8*)p; }
__device__ __forceinline__ short8 ld8(const float* p) {
    float4 a = *(const float4*)p, b = *(const float4*)(p + 4);
    short8 r;
    r[0] = f2b(a.x); r[1] = f2b(a.y); r[2] = f2b(a.z); r[3] = f2b(a.w);
    r[4] = f2b(b.x); r[5] = f2b(b.y); r[6] = f2b(b.z); r[7] = f2b(b.w);
    return r;
}
__device__ __forceinline__ void ldf8(const short* p, float* f) {
    short8 v = *(const short8*)p;
#pragma unroll
    for (int j = 0; j < 8; ++j) f[j] = b2f(v[j]);
}
__device__ __forceinline__ void ldf8(const float* p, float* f) {
    float4 a = *(const float4*)p, b = *(const float4*)(p + 4);
    f[0] = a.x; f[1] = a.y; f[2] = a.z; f[3] = a.w;
    f[4] = b.x; f[5] = b.y; f[6] = b.z; f[7] = b.w;
}
__device__ __forceinline__ void st(short* p, float v) { *p = f2b(v); }
__device__ __forceinline__ void st(float* p, float v) { *p = v; }

__device__ __forceinline__ float red16(float v) {
#pragma unroll
    for (int m = 1; m < 16; m <<= 1) v += __shfl_xor(v, m);
    return v;
}
__device__ __forceinline__ float red8(float v) {
#pragma unroll
    for (int m = 1; m < 8; m <<= 1) v += __shfl_xor(v, m);
    return v;
}

// ---- fast transcendentals (hardware v_exp/v_log/v_rcp; err ~1e-6 rel,
// far below the bf16 quantization of every data buffer) ----
__device__ __forceinline__ float tanh_(float x) {
    float ax = fminf(fabsf(x), 20.f);
    float e = __expf(-2.f * ax);
    float t = (1.f - e) * __builtin_amdgcn_rcpf(1.f + e);
    return copysignf(t, x);
}
__device__ __forceinline__ float artanh_(float x) {
    // callers pass x >= 0 (norms)
    x = fminf(x, 1.f - 1e-7f);
    float x2 = x * x;
    float smal = x * (1.f + x2 * (0.33333334f + x2 * (0.2f + x2 * (0.14285715f + x2 * 0.11111111f))));
    float big = 0.5f * __logf((1.f + x) * __builtin_amdgcn_rcpf(1.f - x));
    return (x < 0.25f) ? smal : big;
}
__device__ __forceinline__ float sigmoidf_(float x) {
    float e = __expf(-x);
    return __builtin_amdgcn_rcpf(1.f + e);
}

// fragment-order index for [DOUT][128] weights: unit ((nt*4+kk)*64+lane), elem e
__device__ __forceinline__ int fragidx(int d, int j) {
    int nt = d >> 4, l15 = d & 15;
    int kk = j >> 5, quad = (j >> 3) & 3, e = j & 7;
    return (((nt << 2) + kk) * 64 + (quad << 4) + l15) * 8 + e;
}

// ---- dtype detector (flag=0 bf16, flag=1 f32) + cnt/fillc zeroing (fused) ----
__global__ void k_detect_zero(const void* hid, int* flag,
                              int* __restrict__ cnt, int* __restrict__ fillc, int N) {
    int t = threadIdx.x;
    int i = blockIdx.x * 256 + t;
    if (i < N) { cnt[i] = 0; fillc[i] = 0; }
    if (blockIdx.x == 0) {
        const short* p = (const short*)hid;
        int bad = 0;
        for (int k = t; k < 4096; k += 256) {
            unsigned u = (unsigned)(unsigned short)p[k];
            unsigned ex = (u >> 7) & 0xFF;
            if (ex >= 128) bad = 1;   // |v| >= 2 or NaN/Inf -> cannot be in-ball bf16 data
        }
        __shared__ int s;
        if (t == 0) s = 0;
        __syncthreads();
        if (bad) atomicOr(&s, 1);
        __syncthreads();
        if (t == 0) *flag = s;
    }
}

// ---------------- prep body (block 0 of k_prep_all) ----------------
template <typename T>
__device__ void prep_body(const T* b1, const T* b2, const T* bl, const T* bih,
                          const T* bhh, const T* Q, const T* ratt,
                          const T* Wih, const T* Whh,
                          float* hb1, float* y2a, float* hb2, float* y2b,
                          float* blf, float* bs256, float* ratf,
                          short* QT, short* Wc, float* sb) {
    int t = threadIdx.x;
    float v1 = (t < 128) ? cv(b1[t]) : 0.f;
    sb[t] = v1 * v1; __syncthreads();
    for (int d = 128; d > 0; d >>= 1) { if (t < d) sb[t] += sb[t + d]; __syncthreads(); }
    float n2a = sb[0]; __syncthreads();
    {
        float un = fmaxf(sqrtf(n2a), MINN);
        float e = tanh_(un), tt = e / un;
        float s = (e > MAXN) ? MAXN / e : 1.f;
        if (t < 128) hb1[t] = s * tt * v1;
        if (t == 0) { float hn = s * e; y2a[0] = hn * hn; }
    }
    float v2 = (t < 64) ? cv(b2[t]) : 0.f;
    sb[t] = v2 * v2; __syncthreads();
    for (int d = 128; d > 0; d >>= 1) { if (t < d) sb[t] += sb[t + d]; __syncthreads(); }
    float n2b = sb[0]; __syncthreads();
    {
        float un = fmaxf(sqrtf(n2b), MINN);
        float e = tanh_(un), tt = e / un;
        float s = (e > MAXN) ? MAXN / e : 1.f;
        if (t < 64) hb2[t] = s * tt * v2;
        if (t == 0) { float hn = s * e; y2b[0] = hn * hn; }
    }
    for (int i = t; i < 64; i += 256) {
        blf[i] = cv(bl[i]);
        ratf[i] = cv(ratt[i]);
    }
    {
        float v = (t < 192) ? (cv(bih[t]) + cv(bhh[t])) : cv(bhh[t - 64]);
        bs256[t] = v;
    }
    for (int i = t; i < 4096; i += 256) { int k = i >> 6, n = i & 63; QT[n * 64 + k] = tb(Q[k * 64 + n]); }
    // GRU combined weight in MFMA-fragment order
    for (int i = t; i < 256 * 128; i += 256) {
        int d = i >> 7, j = i & 127;
        short v;
        if (d < 192) v = (j < 64) ? tb(Wih[d * 64 + j]) : tb(Whh[d * 64 + (j - 64)]);
        else         v = (j < 64) ? (short)0 : tb(Whh[(d - 64) * 64 + (j - 64)]);
        Wc[fragidx(d, j)] = v;
    }
}

template <typename T>
__device__ void wcvt_body(int i, const T* Wl, const T* W1, const T* W2,
                          short* Wlb, short* W1b, short* W2b) {
    if (i < 8192) {
        Wlb[fragidx(i >> 7, i & 127)] = tb(Wl[i]);
    } else if (i < 24576) {
        int i2 = i - 8192;
        W1b[fragidx(i2 >> 7, i2 & 127)] = tb(W1[i2]);
    } else if (i < 32768) {
        int i2 = i - 24576;
        W2b[fragidx(i2 >> 7, i2 & 127)] = tb(W2[i2]);
    }
}

// prep + weight conversion, dtype-branched internally. Launch 129 blocks.
__global__ __launch_bounds__(256) void k_prep_all(
        const void* b1, const void* b2, const void* bl, const void* bih,
        const void* bhh, const void* Q, const void* ratt,
        const void* Wih, const void* Whh,
        const void* Wl, const void* W1, const void* W2,
        float* hb1, float* y2a, float* hb2, float* y2b,
        float* blf, float* bs256, float* ratf,
        short* QT, short* Wc,
        short* Wlb, short* W1b, short* W2b, const int* flag) {
    __shared__ float sb[256];
    int f = *flag;
    if (blockIdx.x == 0) {
        if (f) prep_body<float>((const float*)b1, (const float*)b2, (const float*)bl,
                                (const float*)bih, (const float*)bhh, (const float*)Q,
                                (const float*)ratt, (const float*)Wih, (const float*)Whh,
                                hb1, y2a, hb2, y2b, blf, bs256, ratf, QT, Wc, sb);
        else   prep_body<short>((const short*)b1, (const short*)b2, (const short*)bl,
                                (const short*)bih, (const short*)bhh, (const short*)Q,
                                (const short*)ratt, (const short*)Wih, (const short*)Whh,
                                hb1, y2a, hb2, y2b, blf, bs256, ratf, QT, Wc, sb);
    } else {
        int i = (blockIdx.x - 1) * 256 + threadIdx.x;
        if (f) wcvt_body<float>(i, (const float*)Wl, (const float*)W1, (const float*)W2, Wlb, W1b, W2b);
        else   wcvt_body<short>(i, (const short*)Wl, (const short*)W1, (const short*)W2, Wlb, W1b, W2b);
    }
}

// ---------------- CSR ----------------
__global__ void k_count(const int* __restrict__ src, int E, int* __restrict__ cnt) {
    int i = blockIdx.x * blockDim.x + threadIdx.x;
    if (i < E) atomicAdd(&cnt[src[i]], 1);
}

// ---- multi-block exclusive scan ----
#define SC_CHUNK 2048
__global__ __launch_bounds__(256) void k_scan_bsum(const int* __restrict__ cnt, int N,
                                                   int* __restrict__ bsum) {
    __shared__ int sb[256];
    int t = threadIdx.x;
    int base = blockIdx.x * SC_CHUNK + t * 8;
    int s = 0;
#pragma unroll
    for (int j = 0; j < 8; ++j) { int i = base + j; if (i < N) s += cnt[i]; }
    sb[t] = s; __syncthreads();
    for (int d = 128; d > 0; d >>= 1) { if (t < d) sb[t] += sb[t + d]; __syncthreads(); }
    if (t == 0) bsum[blockIdx.x] = sb[0];
}
__global__ __launch_bounds__(1024) void k_scan_bpre(int* __restrict__ bsum, int nb) {
    __shared__ int sb[1024];
    int t = threadIdx.x;
    sb[t] = (t < nb) ? bsum[t] : 0;
    __syncthreads();
    for (int d = 1; d < 1024; d <<= 1) {
        int u = (t >= d) ? sb[t - d] : 0; __syncthreads();
        sb[t] += u; __syncthreads();
    }
    if (t < nb) bsum[t] = (t == 0) ? 0 : sb[t - 1];
    if (t == 0) bsum[nb] = sb[1023];
}
// scan_write also emits dis[i] = 1/sqrt(deg+1)  (fused former k_dis)
__global__ __launch_bounds__(256) void k_scan_write(const int* __restrict__ cnt,
                                                    int* __restrict__ rowptr, int N,
                                                    const int* __restrict__ bsum, int nb,
                                                    float* __restrict__ dis) {
    __shared__ int sb[256];
    int t = threadIdx.x;
    int b = blockIdx.x;
    int base = b * SC_CHUNK + t * 8;
    int v[8]; int s = 0;
#pragma unroll
    for (int j = 0; j < 8; ++j) { int i = base + j; v[j] = (i < N) ? cnt[i] : 0; s += v[j]; }
    sb[t] = s; __syncthreads();
    for (int d = 1; d < 256; d <<= 1) {
        int u = (t >= d) ? sb[t - d] : 0; __syncthreads();
        sb[t] += u; __syncthreads();
    }
    int run = bsum[b] + ((t == 0) ? 0 : sb[t - 1]);
#pragma unroll
    for (int j = 0; j < 8; ++j) {
        int i = base + j;
        if (i < N) {
            rowptr[i] = run;
            dis[i] = 1.f / sqrtf((float)(v[j] + 1));
        }
        run += v[j];
    }
    if (b == 0 && t == 0) rowptr[N] = bsum[nb];
}

// fill writes interleaved edge records {col, weight} (weight = dis[s]*dis[d])
__global__ void k_fill(const int* __restrict__ src, const int* __restrict__ dst, int E,
                       const int* __restrict__ rowptr, int* __restrict__ fill,
                       int2* __restrict__ edge, const float* __restrict__ dis) {
    int i = blockIdx.x * blockDim.x + threadIdx.x;
    if (i < E) {
        int s = src[i], d = dst[i];
        int p = rowptr[s] + atomicAdd(&fill[s], 1);
        int2 e; e.x = d; e.y = __float_as_int(dis[s] * dis[d]);
        edge[p] = e;
    }
}

// --------- fused HTA attention: logmap0 -> scores -> ONLINE softmax -> combine ----
template <typename T>
__device__ void att_body(const T* hid, const short* QT, const float* ratf,
                         bf16* Hb, int N, int win) {
    int wid = threadIdx.x >> 6, lane = threadIdx.x & 63;
    int row0 = blockIdx.x * 64 + wid * 16;
    if (row0 >= N) return;
    int l15 = lane & 15, quad = lane >> 4;
    int node = row0 + l15;
    int nodeC = (node < N) ? node : (N - 1);
    // hoisted QT fragments (loop-invariant)
    short8 qb0[4], qb1[4];
    float rw[4];
#pragma unroll
    for (int nt = 0; nt < 4; ++nt) {
        qb0[nt] = *(const short8*)(QT + (size_t)(nt * 16 + l15) * 64 + quad * 8);
        qb1[nt] = *(const short8*)(QT + (size_t)(nt * 16 + l15) * 64 + 32 + quad * 8);
        rw[nt] = ratf[nt * 16 + l15];
    }
    float m = -1e30f, srun = 0.f;
    float h[16];
#pragma unroll
    for (int j = 0; j < 16; ++j) h[j] = 0.f;
    for (int w = 0; w < win; ++w) {
        const T* Hrow = hid + ((size_t)w * N + nodeC) * 64 + quad * 8;
        float f0[8], f1[8];
        ldf8(Hrow, f0); ldf8(Hrow + 32, f1);
        float sq = 0.f;
#pragma unroll
        for (int j = 0; j < 8; ++j) sq += f0[j] * f0[j] + f1[j] * f1[j];
        sq += __shfl_xor(sq, 16); sq += __shfl_xor(sq, 32);
        float pn = fmaxf(sqrtf(sq), MINN);
        float lt = artanh_(pn) / pn;
        short8 s0, s1;
#pragma unroll
        for (int j = 0; j < 8; ++j) { s0[j] = f2b(lt * f0[j]); s1[j] = f2b(lt * f1[j]); }
        f32x4 acc[4];
#pragma unroll
        for (int nt = 0; nt < 4; ++nt) acc[nt] = (f32x4){0.f, 0.f, 0.f, 0.f};
#pragma unroll
        for (int nt = 0; nt < 4; ++nt) {
            acc[nt] = __builtin_amdgcn_mfma_f32_16x16x32_bf16(s0, qb0[nt], acc[nt], 0, 0, 0);
            acc[nt] = __builtin_amdgcn_mfma_f32_16x16x32_bf16(s1, qb1[nt], acc[nt], 0, 0, 0);
        }
        float er[4];
#pragma unroll
        for (int r = 0; r < 4; ++r) {
            float s = 0.f;
#pragma unroll
            for (int nt = 0; nt < 4; ++nt) s += tanh_(acc[nt][r]) * rw[nt];
            er[r] = red16(s);       // all lanes of this quad hold E[row0+quad*4+r]
        }
        // broadcast: this lane needs E of node row0+l15 (held by quad l15>>2, slot l15&3)
        int srcLane = (l15 >> 2) << 4;
        float t0 = __shfl(er[0], srcLane);
        float t1 = __shfl(er[1], srcLane);
        float t2 = __shfl(er[2], srcLane);
        float t3 = __shfl(er[3], srcLane);
        int rr = l15 & 3;
        float Eval = (rr == 0) ? t0 : (rr == 1) ? t1 : (rr == 2) ? t2 : t3;
        // online softmax update
        float mn = fmaxf(m, Eval);
        float c = __expf(m - mn);
        float p = __expf(Eval - mn);
        m = mn;
        srun = srun * c + p;
#pragma unroll
        for (int j = 0; j < 8; ++j) {
            h[j]     = h[j]     * c + p * (lt * f0[j]);
            h[8 + j] = h[8 + j] * c + p * (lt * f1[j]);
        }
    }
    if (node < N) {
        float den = srun * (float)win;
        short8 o0, o1;
#pragma unroll
        for (int j = 0; j < 8; ++j) { o0[j] = f2b(h[j] / den); o1[j] = f2b(h[8 + j] / den); }
        *(short8*)((short*)Hb + (size_t)node * 64 + quad * 8) = o0;
        *(short8*)((short*)Hb + (size_t)node * 64 + 32 + quad * 8) = o1;
    }
}
__global__ __launch_bounds__(256) void k_att(const void* hid, const short* __restrict__ QT,
                                             const float* __restrict__ ratf,
                                             bf16* __restrict__ Hb, int N, int win, const int* flag) {
    if (*flag) att_body<float>((const float*)hid, QT, ratf, Hb, N, win);
    else       att_body<short>((const short*)hid, QT, ratf, Hb, N, win);
}

// --------- FUSED: initial linear + toHyperX + concat -> (LDS) -> conv1 linear ----
#define SXSTR 136
template <typename T>
__device__ void lin0c1_body(const T* feat, const short* Wl, const float* blf, const T* hid,
                            int win, const short* W1, const float* hb1, const float* y2p,
                            bf16* outA, int N, short* sX) {
    int t = threadIdx.x;
    int wid = t >> 6, lane = t & 63;
    int row0 = blockIdx.x * 64 + wid * 16;
    if (row0 >= N) return;
    int l15 = lane & 15, quad = lane >> 4;
    short* sx = sX + wid * 16 * SXSTR;     // this wave's 16x128 tile (padded)
    // ---- phase 1: lin0 GEMM (feat @ Wl^T) ----
    const short8* Wf = (const short8*)Wl;
    f32x4 acc[4];
#pragma unroll
    for (int nt = 0; nt < 4; ++nt) acc[nt] = (f32x4){0.f, 0.f, 0.f, 0.f};
    const T* Arow = feat + (size_t)(row0 + l15) * 128 + quad * 8;
#pragma unroll
    for (int kk = 0; kk < 4; ++kk) {
        short8 a = ld8(Arow + kk * 32);
#pragma unroll
        for (int nt = 0; nt < 4; ++nt) {
            short8 b = Wf[(nt * 4 + kk) * 64 + lane];
            acc[nt] = __builtin_amdgcn_mfma_f32_16x16x32_bf16(a, b, acc[nt], 0, 0, 0);
        }
    }
    float bv[4];
#pragma unroll
    for (int nt = 0; nt < 4; ++nt) bv[nt] = blf[nt * 16 + l15];
    float xn_r[4];
#pragma unroll
    for (int r = 0; r < 4; ++r) {
        int row = row0 + quad * 4 + r;
        float g[4], u2 = 0.f;
#pragma unroll
        for (int nt = 0; nt < 4; ++nt) { g[nt] = acc[nt][r] + bv[nt]; u2 += g[nt] * g[nt]; }
        u2 = red16(u2);
        float un = fmaxf(sqrtf(u2), MINN);
        float e = tanh_(un), tt = e / un;
        float s1 = (e > MAXN) ? MAXN / e : 1.f;
        float x0n = s1 * e;
        float hv[4], h2 = 0.f;
#pragma unroll
        for (int nt = 0; nt < 4; ++nt) {
            hv[nt] = cv(hid[((size_t)(win - 1) * N + row) * 64 + nt * 16 + l15]);
            h2 += hv[nt] * hv[nt];
        }
        h2 = red16(h2);
        float n128 = sqrtf(x0n * x0n + h2);
        float s2 = (n128 > MAXN) ? MAXN / n128 : 1.f;
        short* srow = sx + (quad * 4 + r) * SXSTR;
#pragma unroll
        for (int nt = 0; nt < 4; ++nt) {
            srow[nt * 16 + l15] = f2b(s2 * s1 * tt * g[nt]);
            srow[64 + nt * 16 + l15] = f2b(s2 * hv[nt]);
        }
        xn_r[r] = fmaxf(fminf(n128, MAXN), MINN);
    }
    // ---- phase 2: conv1 GEMM from LDS (wave-internal dep; no barrier) ----
    const short8* W1f = (const short8*)W1;
    f32x4 acc2[8];
#pragma unroll
    for (int nt = 0; nt < 8; ++nt) acc2[nt] = (f32x4){0.f, 0.f, 0.f, 0.f};
    const short* Ax = sx + l15 * SXSTR + quad * 8;
#pragma unroll
    for (int kk = 0; kk < 4; ++kk) {
        short8 a = *(const short8*)(Ax + kk * 32);
#pragma unroll
        for (int nt = 0; nt < 8; ++nt) {
            short8 b = W1f[(nt * 4 + kk) * 64 + lane];
            acc2[nt] = __builtin_amdgcn_mfma_f32_16x16x32_bf16(a, b, acc2[nt], 0, 0, 0);
        }
    }
    float y2 = y2p[0];
    float hbv[8];
#pragma unroll
    for (int nt = 0; nt < 8; ++nt) hbv[nt] = hb1[nt * 16 + l15];
#pragma unroll
    for (int r = 0; r < 4; ++r) {
        int row = row0 + quad * 4 + r;
        float mx[8], m2 = 0.f;
#pragma unroll
        for (int nt = 0; nt < 8; ++nt) { mx[nt] = acc2[nt][r]; m2 += mx[nt] * mx[nt]; }
        m2 = red16(m2);
        float mxn = fmaxf(sqrtf(m2), MINN);
        float xn = xn_r[r];
        float at = artanh_(xn);
        float f = (m2 == 0.f) ? 0.f : tanh_(mxn / xn * at) / mxn;
        float rn = f * mxn;
        float s1 = (rn > MAXN) ? MAXN / rn : 1.f;
        float a_ = s1 * f, mvn = s1 * rn;
        float x2 = mvn * mvn;
        float xy = 0.f;
#pragma unroll
        for (int nt = 0; nt < 8; ++nt) xy += (a_ * mx[nt]) * hbv[nt];
        xy = red16(xy);
        float co = 1.f + 2.f * xy + y2, cx = 1.f - x2;
        float den = fmaxf(1.f + 2.f * xy + x2 * y2, MINN);
        float o[8], on2 = 0.f;
#pragma unroll
        for (int nt = 0; nt < 8; ++nt) { o[nt] = (co * a_ * mx[nt] + cx * hbv[nt]) / den; on2 += o[nt] * o[nt]; }
        on2 = red16(on2);
        float on = sqrtf(on2);
        float s3 = (on > MAXN) ? MAXN / on : 1.f;
        float hn = fmaxf(s3 * on, MINN);
        float lt = artanh_(hn) / hn;
#pragma unroll
        for (int nt = 0; nt < 8; ++nt)
            ((short*)outA)[(size_t)row * 128 + nt * 16 + l15] = f2b(lt * s3 * o[nt]);
    }
}
__global__ __launch_bounds__(256) void k_lin0c1(const void* feat, const short* __restrict__ Wl,
                                                const float* __restrict__ blf, const void* hid,
                                                int win, const short* __restrict__ W1,
                                                const float* __restrict__ hb1, const float* __restrict__ y2a,
                                                bf16* __restrict__ outA, int N, const int* flag) {
    __shared__ short sX[4 * 16 * SXSTR];   // 17408 B
    if (*flag) lin0c1_body<float>((const float*)feat, Wl, blf, (const float*)hid, win, W1, hb1, y2a, outA, N, sX);
    else       lin0c1_body<short>((const short*)feat, Wl, blf, (const short*)hid, win, W1, hb1, y2a, outA, N, sX);
}

// ------- conv2 linear: GEMM fused with matvec->proj->madd(hb)->proj->logmap0 ----
template <int DOUT>
__global__ __launch_bounds__(256) void k_conv_lin(const bf16* __restrict__ in, const short* __restrict__ W,
                                                  const float* __restrict__ hb, const float* __restrict__ y2p,
                                                  const float* __restrict__ xnorm,
                                                  bf16* __restrict__ out, int N) {
    constexpr int NT = DOUT / 16;
    int t = threadIdx.x;
    int wid = t >> 6, lane = t & 63;
    int row0 = blockIdx.x * 64 + wid * 16;
    if (row0 >= N) return;
    int l15 = lane & 15, quad = lane >> 4;
    const short8* Wf = (const short8*)W;
    f32x4 acc[NT];
#pragma unroll
    for (int nt = 0; nt < NT; ++nt) acc[nt] = (f32x4){0.f, 0.f, 0.f, 0.f};
    const short* Arow = (const short*)in + (size_t)(row0 + l15) * 128 + quad * 8;
#pragma unroll
    for (int kk = 0; kk < 4; ++kk) {
        short8 a = *(const short8*)(Arow + kk * 32);
#pragma unroll
        for (int nt = 0; nt < NT; ++nt) {
            short8 b = Wf[(nt * 4 + kk) * 64 + lane];
            acc[nt] = __builtin_amdgcn_mfma_f32_16x16x32_bf16(a, b, acc[nt], 0, 0, 0);
        }
    }
    float y2 = y2p[0];
    float hbv[NT];
#pragma unroll
    for (int nt = 0; nt < NT; ++nt) hbv[nt] = hb[nt * 16 + l15];
#pragma unroll
    for (int r = 0; r < 4; ++r) {
        int row = row0 + quad * 4 + r;
        float mx[NT], m2 = 0.f;
#pragma unroll
        for (int nt = 0; nt < NT; ++nt) { mx[nt] = acc[nt][r]; m2 += mx[nt] * mx[nt]; }
        m2 = red16(m2);
        float mxn = fmaxf(sqrtf(m2), MINN);
        float xn = xnorm[row];
        float at = artanh_(xn);
        float f = (m2 == 0.f) ? 0.f : tanh_(mxn / xn * at) / mxn;
        float rn = f * mxn;
        float s1 = (rn > MAXN) ? MAXN / rn : 1.f;
        float a_ = s1 * f, mvn = s1 * rn;
        float x2 = mvn * mvn;
        float xy = 0.f;
#pragma unroll
        for (int nt = 0; nt < NT; ++nt) xy += (a_ * mx[nt]) * hbv[nt];
        xy = red16(xy);
        float co = 1.f + 2.f * xy + y2, cx = 1.f - x2;
        float den = fmaxf(1.f + 2.f * xy + x2 * y2, MINN);
        float o[NT], on2 = 0.f;
#pragma unroll
        for (int nt = 0; nt < NT; ++nt) { o[nt] = (co * a_ * mx[nt] + cx * hbv[nt]) / den; on2 += o[nt] * o[nt]; }
        on2 = red16(on2);
        float on = sqrtf(on2);
        float s3 = (on > MAXN) ? MAXN / on : 1.f;
        float hn = fmaxf(s3 * on, MINN);
        float lt = artanh_(hn) / hn;
#pragma unroll
        for (int nt = 0; nt < NT; ++nt)
            ((short*)out)[(size_t)row * 128 + nt * 16 + l15] = f2b(lt * s3 * o[nt]);
    }
}

// --------- agg (conv1, D=128): 4 nodes/wave, 16 lanes/node, dwordx4 -------
// Edge records prefetched 1 deep: edge[j+1] issues before the dependent row gather of j.
__global__ __launch_bounds__(256) void k_agg2(const bf16* __restrict__ xt, const int* __restrict__ rowptr,
                                              const int2* __restrict__ edge,
                                              const float* __restrict__ dis,
                                              bf16* __restrict__ out, float* __restrict__ xnorm, int N) {
    int wid = threadIdx.x >> 6, lane = threadIdx.x & 63;
    int g = lane >> 4, l15 = lane & 15;
    int i = blockIdx.x * 16 + wid * 4 + g;
    bool act = (i < N);
    int ii = act ? i : (N - 1);
    const u32x4* xq = (const u32x4*)xt;            // 16 u32x4 per 128-feat row
    float di = dis[ii];
    float w0 = di * di;
    u32x4 d0 = xq[(size_t)ii * 16 + l15];
    float a[8];
#pragma unroll
    for (int k = 0; k < 4; ++k) { a[2 * k] = w0 * lo16f(d0[k]); a[2 * k + 1] = w0 * hi16f(d0[k]); }
    int e0 = rowptr[ii], e1 = act ? rowptr[ii + 1] : e0;
    int2 e;
    if (e0 < e1) e = edge[e0];
    for (int j = e0; j < e1; ++j) {
        int2 cur = e;
        if (j + 1 < e1) e = edge[j + 1];   // prefetch next record
        float w = __int_as_float(cur.y);
        u32x4 d = xq[(size_t)cur.x * 16 + l15];
#pragma unroll
        for (int k = 0; k < 4; ++k) { a[2 * k] += w * lo16f(d[k]); a[2 * k + 1] += w * hi16f(d[k]); }
    }
    float sq = 0.f;
#pragma unroll
    for (int k = 0; k < 8; ++k) sq += a[k] * a[k];
    float an = fmaxf(sqrtf(red16(sq)), MINN);
    float e1t = tanh_(an), t1 = e1t / an;
    float s1 = (e1t > MAXN) ? MAXN / e1t : 1.f;
    float hn = fmaxf(s1 * e1t, MINN);
    float lt = artanh_(hn) / hn;
    float sht = s1 * t1 * lt;
    float v[8], v2 = 0.f;
#pragma unroll
    for (int k = 0; k < 8; ++k) {
        float t = sht * a[k];
        t = (t >= 0.f) ? t : 0.01f * t;
        v[k] = t; v2 += t * t;
    }
    float tn = fmaxf(sqrtf(red16(v2)), MINN);
    float e2 = tanh_(tn), t2 = e2 / tn;
    float s2 = (e2 > MAXN) ? MAXN / e2 : 1.f;
    float sc = s2 * t2;
    if (act) {
        u32x4 o;
#pragma unroll
        for (int k = 0; k < 4; ++k) o[k] = pk2(sc * v[2 * k], sc * v[2 * k + 1]);
        ((u32x4*)out)[(size_t)i * 16 + l15] = o;
        if (l15 == 0) xnorm[i] = fmaxf(fminf(e2, MAXN), MINN);
    }
}

// --------- agg (conv2, D=64) + FINAL logmap0: 8 nodes/wave, 8 lanes/node --
__global__ __launch_bounds__(256) void k_agg1f(const bf16* __restrict__ xt, const int* __restrict__ rowptr,
                                               const int2* __restrict__ edge,
                                               const float* __restrict__ dis,
                                               bf16* __restrict__ out, const bf16* __restrict__ Hb, int N) {
    int wid = threadIdx.x >> 6, lane = threadIdx.x & 63;
    int g = lane >> 3, l7 = lane & 7;
    int i = blockIdx.x * 32 + wid * 8 + g;
    bool act = (i < N);
    int ii = act ? i : (N - 1);
    const u32x4* xq = (const u32x4*)xt;            // row stride 16 u32x4; feats = first 8
    float di = dis[ii];
    float w0 = di * di;
    u32x4 d0 = xq[(size_t)ii * 16 + l7];
    float a[8];
#pragma unroll
    for (int k = 0; k < 4; ++k) { a[2 * k] = w0 * lo16f(d0[k]); a[2 * k + 1] = w0 * hi16f(d0[k]); }
    int e0 = rowptr[ii], e1 = act ? rowptr[ii + 1] : e0;
    int2 e;
    if (e0 < e1) e = edge[e0];
    for (int j = e0; j < e1; ++j) {
        int2 cur = e;
        if (j + 1 < e1) e = edge[j + 1];   // prefetch next record
        float w = __int_as_float(cur.y);
        u32x4 d = xq[(size_t)cur.x * 16 + l7];
#pragma unroll
        for (int k = 0; k < 4; ++k) { a[2 * k] += w * lo16f(d[k]); a[2 * k + 1] += w * hi16f(d[k]); }
    }
    float sq = 0.f;
#pragma unroll
    for (int k = 0; k < 8; ++k) sq += a[k] * a[k];
    float an = fmaxf(sqrtf(red8(sq)), MINN);
    float e1t = tanh_(an), t1 = e1t / an;
    float s1 = (e1t > MAXN) ? MAXN / e1t : 1.f;
    float hn = fmaxf(s1 * e1t, MINN);
    float lt = artanh_(hn) / hn;
    float sht = s1 * t1 * lt;
    float v[8], v2 = 0.f;
#pragma unroll
    for (int k = 0; k < 8; ++k) {
        float t = sht * a[k];
        t = (t >= 0.f) ? t : 0.01f * t;
        v[k] = t; v2 += t * t;
    }
    float tn = fmaxf(sqrtf(red8(v2)), MINN);
    float e2 = tanh_(tn), t2 = e2 / tn;
    float s2 = (e2 > MAXN) ? MAXN / e2 : 1.f;
    float sc = s2 * t2;
    float xnf = fmaxf(fminf(s2 * e2, MAXN), MINN);
    float lt2 = artanh_(xnf) / xnf;
    sc *= lt2;
    if (act) {
        u32x4 o;
#pragma unroll
        for (int k = 0; k < 4; ++k) o[k] = pk2(sc * v[2 * k], sc * v[2 * k + 1]);
        u32x4* od = (u32x4*)out;
        od[(size_t)i * 16 + l7] = o;
        od[(size_t)i * 16 + 8 + l7] = ((const u32x4*)Hb)[(size_t)i * 8 + l7];
    }
}

// --------- GRU fused + expmap0/proj -> out (dtype-branched) -----
template <typename OT>
__device__ void gru_body(const bf16* cat, const float* bs, const bf16* Hb,
                         OT* out, int N, const short8* sW) {
    int t = threadIdx.x;
    int wid = t >> 6, lane = t & 63;
    int row0 = blockIdx.x * 64 + wid * 16;
    if (row0 >= N) return;
    int l15 = lane & 15, quad = lane >> 4;
    f32x4 acc[16];
#pragma unroll
    for (int nt = 0; nt < 16; ++nt) acc[nt] = (f32x4){0.f, 0.f, 0.f, 0.f};
    const short* Arow = (const short*)cat + (size_t)(row0 + l15) * 128 + quad * 8;
#pragma unroll
    for (int kk = 0; kk < 4; ++kk) {
        short8 a = *(const short8*)(Arow + kk * 32);
#pragma unroll
        for (int nt = 0; nt < 16; ++nt) {
            short8 b = sW[(nt * 4 + kk) * 64 + lane];
            acc[nt] = __builtin_amdgcn_mfma_f32_16x16x32_bf16(a, b, acc[nt], 0, 0, 0);
        }
    }
#pragma unroll
    for (int r = 0; r < 4; ++r) {
        int row = row0 + quad * 4 + r;
        float zv[4], z2 = 0.f;
#pragma unroll
        for (int nt = 0; nt < 4; ++nt) {
            int c = nt * 16 + l15;
            float gr = acc[nt][r] + bs[c];
            float gz = acc[nt + 4][r] + bs[c + 64];
            float gn = acc[nt + 8][r] + bs[c + 128];
            float hn = acc[nt + 12][r] + bs[c + 192];
            float hv = b2f(((const short*)Hb)[(size_t)row * 64 + c]);
            float rr = sigmoidf_(gr), zz = sigmoidf_(gz);
            float nn = tanh_(gn + (rr - 1.f) * hn);
            zv[nt] = (1.f - zz) * nn + zz * hv;
            z2 += zv[nt] * zv[nt];
        }
        z2 = red16(z2);
        float un = fmaxf(sqrtf(z2), MINN);
        float e = tanh_(un), tt = e / un;
        float s = (e > MAXN) ? MAXN / e : 1.f;
#pragma unroll
        for (int nt = 0; nt < 4; ++nt)
            st(&out[(size_t)row * 64 + nt * 16 + l15], s * tt * zv[nt]);
    }
}
__global__ __launch_bounds__(256) void k_gru(const bf16* __restrict__ cat, const short* __restrict__ Wc,
                                             const float* __restrict__ bs, const bf16* __restrict__ Hb,
                                             void* out, int N, const int* flag) {
    __shared__ short8 sW[4096];        // 64KB: 256x128 bf16, single allocation for both paths
    int t = threadIdx.x;
#pragma unroll
    for (int u = 0; u < 16; ++u) sW[u * 256 + t] = ((const short8*)Wc)[u * 256 + t];
    __syncthreads();
    if (*flag) gru_body<float>(cat, bs, Hb, (float*)out, N, sW);
    else       gru_body<short>(cat, bs, Hb, (short*)out, N, sW);
}

extern "C" void kernel_launch(void* const* d_in, const int* in_sizes, int n_in,
                              void* d_out, int out_size, void* d_ws, size_t ws_size,
                              hipStream_t stream) {
    const int E = in_sizes[0] / 2;
    const int N = in_sizes[1] / 128;
    int win = in_sizes[14] / (N * 64); if (win > 8) win = 8;

    char* wp = (char*)d_ws;
    auto alloc = [&](size_t bytes) -> void* {
        void* p = (void*)wp;
        wp += (bytes + 255) & ~(size_t)255;
        return p;
    };
    bf16* bufA = (bf16*)alloc((size_t)N * 128 * 2);
    bf16* bufB = (bf16*)alloc((size_t)N * 128 * 2);
    bf16* Hbf  = (bf16*)alloc((size_t)N * 64 * 2);
    float* xnorm = (float*)alloc((size_t)N * 4);
    int* cnt = (int*)alloc((size_t)N * 4);
    int* fillc = (int*)alloc((size_t)N * 4);
    int* rowptr = (int*)alloc((size_t)(N + 1) * 4);
    float* dis = (float*)alloc((size_t)N * 4);
    int2* edge = (int2*)alloc((size_t)E * 8);
    int* bsum = (int*)alloc((size_t)1025 * 4);
    float* hb1 = (float*)alloc(128 * 4);
    float* y2a = (float*)alloc(256);
    float* hb2 = (float*)alloc(64 * 4);
    float* y2b = (float*)alloc(256);
    float* blf = (float*)alloc(64 * 4);
    float* bs256 = (float*)alloc(256 * 4);
    float* ratf = (float*)alloc(64 * 4);
    short* QT = (short*)alloc(4096 * 2);
    short* Wc = (short*)alloc((size_t)256 * 128 * 2);
    short* Wlb = (short*)alloc((size_t)8192 * 2);
    short* W1b = (short*)alloc((size_t)16384 * 2);
    short* W2b = (short*)alloc((size_t)8192 * 2);
    int* flag = (int*)alloc(256);
    (void)ws_size; (void)out_size; (void)n_in;

    const int* ei = (const int*)d_in[0];

    // dtype detect + cnt/fillc zeroing (fused, replaces detect + memset)
    k_detect_zero<<<(N + 255) / 256, 256, 0, stream>>>(d_in[14], flag, cnt, fillc, N);

    // prep + weight conversion (dtype-branched internally; 1 launch)
    k_prep_all<<<129, 256, 0, stream>>>(d_in[5], d_in[7], d_in[3], d_in[12], d_in[13],
                                        d_in[8], d_in[9], d_in[10], d_in[11],
                                        d_in[2], d_in[4], d_in[6],
                                        hb1, y2a, hb2, y2b, blf, bs256, ratf,
                                        QT, Wc, Wlb, W1b, W2b, flag);
    // CSR build (dtype-free)
    k_count<<<(E + 255) / 256, 256, 0, stream>>>(ei, E, cnt);
    {
        int nb = (N + SC_CHUNK - 1) / SC_CHUNK;   // <=1024 for N<=2M
        k_scan_bsum<<<nb, 256, 0, stream>>>(cnt, N, bsum);
        k_scan_bpre<<<1, 1024, 0, stream>>>(bsum, nb);
        k_scan_write<<<nb, 256, 0, stream>>>(cnt, rowptr, N, bsum, nb, dis);
    }
    k_fill<<<(E + 255) / 256, 256, 0, stream>>>(ei, ei + E, E, rowptr, fillc, edge, dis);
    // HTA window attention: single-pass online-softmax fusion
    k_att<<<(N + 63) / 64, 256, 0, stream>>>(d_in[14], QT, ratf, Hbf, N, win, flag);
    // fused initial linear + toHyperX + concat + conv1 linear
    k_lin0c1<<<(N + 63) / 64, 256, 0, stream>>>(d_in[1], Wlb, blf, d_in[14], win,
                                                W1b, hb1, y2a, bufA, N, flag);
    k_agg2<<<(N + 15) / 16, 256, 0, stream>>>(bufA, rowptr, edge, dis, bufB, xnorm, N);
    // conv2
    k_conv_lin<64><<<(N + 63) / 64, 256, 0, stream>>>(bufB, W2b, hb2, y2b, xnorm, bufB, N);
    k_agg1f<<<(N + 31) / 32, 256, 0, stream>>>(bufB, rowptr, edge, dis, bufA, Hbf, N);
    // GRU fused + toHyperX -> out (output dtype = detected input dtype)
    k_gru<<<(N + 63) / 64, 256, 0, stream>>>(bufA, Wc, bs256, Hbf, d_out, N, flag);
}